// Round 8
// baseline (200.252 us; speedup 1.0000x reference)
//
#include <hip/hip_runtime.h>
#include <math.h>

#define NHEAD  16
#define DHEAD  64
#define DLAT   32
#define TSEQ   2048
#define NBATCH 2
#define CDIM   1024
#define MROWS  (NBATCH*TSEQ)   // 4096

typedef __attribute__((ext_vector_type(8))) short bf16x8;
typedef __attribute__((ext_vector_type(4))) short bf16x4;
typedef __attribute__((ext_vector_type(4))) float f32x4;

#define AS1 __attribute__((address_space(1)))
#define AS3 __attribute__((address_space(3)))

__device__ __forceinline__ unsigned short f2bf(float f) {
    union { float f; unsigned u; } v; v.f = f;
    unsigned r = v.u + 0x7fff + ((v.u >> 16) & 1);   // RNE
    return (unsigned short)(r >> 16);
}

// pack two floats -> bf16 pair (RNE), lo | hi<<16
__device__ __forceinline__ unsigned pk2(float lo, float hi) {
    return (unsigned)f2bf(lo) | ((unsigned)f2bf(hi) << 16);
}

// pack bf16(lo)|bf16(hi)<<16 by truncation — one v_perm_b32
__device__ __forceinline__ unsigned pack_trunc(float hi, float lo) {
    return __builtin_amdgcn_perm(__float_as_uint(hi), __float_as_uint(lo), 0x07060302u);
}

__device__ __forceinline__ void gld_lds16(const unsigned short* g, unsigned short* l) {
    __builtin_amdgcn_global_load_lds((const AS1 void*)g, (AS3 void*)l, 16, 0, 0);
}

// 16x16x16 bf16 MFMA: builtin if present, else raw instruction (gfx950 has it)
__device__ __forceinline__ f32x4 mfma_16x16x16_bf16(bf16x4 a, bf16x4 b, f32x4 c) {
#if __has_builtin(__builtin_amdgcn_mfma_f32_16x16x16bf16_1k)
    return __builtin_amdgcn_mfma_f32_16x16x16bf16_1k(a, b, c, 0, 0, 0);
#else
    asm volatile("v_mfma_f32_16x16x16_bf16 %0, %1, %2, %0\n\ts_nop 4"
                 : "+v"(c) : "v"(a), "v"(b));
    return c;
#endif
}

// ---------------- fp32 -> bf16: x and all six weights in ONE launch ----------------
__global__ __launch_bounds__(256) void cvt_all(
        const float* __restrict__ x,  const float* __restrict__ wq,
        const float* __restrict__ wk, const float* __restrict__ wv,
        const float* __restrict__ wc, const float* __restrict__ wku,
        const float* __restrict__ wvu,
        unsigned short* __restrict__ xb, unsigned short* __restrict__ wall) {
    int i = (blockIdx.x * 256 + threadIdx.x) * 4;
    const float* src; unsigned short* dst; int off;
    if      (i < 4194304) { src = x;   dst = xb;             off = 0;       }
    else if (i < 5242880) { src = wq;  dst = wall;           off = 4194304; }
    else if (i < 5767168) { src = wk;  dst = wall + 1048576; off = 5242880; }
    else if (i < 6291456) { src = wv;  dst = wall + 1572864; off = 5767168; }
    else if (i < 7340032) { src = wc;  dst = wall + 2097152; off = 6291456; }
    else if (i < 7342080) { src = wku; dst = wall + 3145728; off = 7340032; }
    else                  { src = wvu; dst = wall + 3147776; off = 7342080; }
    float4 v = *(const float4*)(src + (i - off));
    ushort4 o = { f2bf(v.x), f2bf(v.y), f2bf(v.z), f2bf(v.w) };
    *(ushort4*)(dst + (i - off)) = o;
}

// ---------------- MFMA GEMM core: 128x128 tile, BK=32, 8 waves (512 thr) ----------------
// R12: 2x waves/CU vs 4-wave blocks; same 2-barrier schedule. Measured win (R6).
__device__ __forceinline__ void gemm_core(
        const unsigned short* __restrict__ A, const unsigned short* __restrict__ W,
        int K, int bm, int bn, unsigned short* As, unsigned short* Bs,
        f32x4 (&acc)[4][2]) {
    const int tid = threadIdx.x;
    const int w = tid >> 6, lane = tid & 63;
    const int quad = lane >> 4, l16 = lane & 15;
    const int wm = (w >> 2) * 64, wn = (w & 3) * 32;

    // staging: 512 threads x 16B = one 128x32 bf16 tile per issue
    const int sr = tid >> 2;           // row 0..127
    const int sc = (tid & 3) * 8;      // col elem
    const unsigned short* Ag0 = A + (size_t)(bm + sr) * K + sc;
    const unsigned short* Wg0 = W + (size_t)(bn + sr) * K + sc;
    unsigned short* AsD = &As[(w*16) * 32];   // wave w: rows w*16..w*16+15, linear
    unsigned short* BsD = &Bs[(w*16) * 32];

    for (int k0 = 0; k0 < K; k0 += 32) {
        gld_lds16(Ag0 + k0, AsD);
        gld_lds16(Wg0 + k0, BsD);
        __syncthreads();
        bf16x8 af[4], bf[2];
        #pragma unroll
        for (int t = 0; t < 4; ++t)
            af[t] = *(const bf16x8*)&As[(wm + t*16 + l16)*32 + quad*8];
        #pragma unroll
        for (int c = 0; c < 2; ++c)
            bf[c] = *(const bf16x8*)&Bs[(wn + c*16 + l16)*32 + quad*8];
        #pragma unroll
        for (int t = 0; t < 4; ++t)
            #pragma unroll
            for (int c = 0; c < 2; ++c)
                acc[t][c] = __builtin_amdgcn_mfma_f32_16x16x32_bf16(af[t], bf[c], acc[t][c], 0, 0, 0);
        __syncthreads();
    }
}

__global__ __launch_bounds__(512) void gemm_proj(
        const unsigned short* __restrict__ A, const unsigned short* __restrict__ W,
        float* __restrict__ qproj, float* __restrict__ okl, float* __restrict__ ovl,
        int K) {
    __shared__ unsigned short As[128*32];
    __shared__ unsigned short Bs[128*32];
    const int bm = blockIdx.y * 128, bn = blockIdx.x * 128;
    f32x4 acc[4][2] = {};
    gemm_core(A, W, K, bm, bn, As, Bs, acc);

    const int tid = threadIdx.x;
    const int w = tid >> 6, lane = tid & 63;
    const int quad = lane >> 4, l16 = lane & 15;
    const int wm = (w >> 2) * 64, wn = (w & 3) * 32;

    float* base; int ldo;
    if (bn < 1024)      { base = qproj + bn;        ldo = 1024; }
    else if (bn < 1536) { base = okl + (bn - 1024); ldo = 512;  }
    else                { base = ovl + (bn - 1536); ldo = 512;  }

    #pragma unroll
    for (int t = 0; t < 4; ++t)
        #pragma unroll
        for (int c = 0; c < 2; ++c)
            #pragma unroll
            for (int r = 0; r < 4; ++r) {
                int row = bm + wm + t*16 + quad*4 + r;
                int col = wn + c*16 + l16;
                base[(size_t)row * ldo + col] = acc[t][c][r];
            }
}

__global__ __launch_bounds__(512) void gemm_out(
        const unsigned short* __restrict__ A, const unsigned short* __restrict__ W,
        float* __restrict__ O, int N, int K) {
    __shared__ unsigned short As[128*32];
    __shared__ unsigned short Bs[128*32];
    const int bm = blockIdx.y * 128, bn = blockIdx.x * 128;
    f32x4 acc[4][2] = {};
    gemm_core(A, W, K, bm, bn, As, Bs, acc);

    const int tid = threadIdx.x;
    const int w = tid >> 6, lane = tid & 63;
    const int quad = lane >> 4, l16 = lane & 15;
    const int wm = (w >> 2) * 64, wn = (w & 3) * 32;
    #pragma unroll
    for (int t = 0; t < 4; ++t)
        #pragma unroll
        for (int c = 0; c < 2; ++c)
            #pragma unroll
            for (int r = 0; r < 4; ++r) {
                int row = bm + wm + t*16 + quad*4 + r;
                int col = bn + wn + c*16 + l16;
                O[(size_t)row * N + col] = acc[t][c][r];
            }
}

// ---------------- fused latent up-proj (k,v) via MFMA + q load + RoPE ----------------
// q carries 0.125*log2(e) so flash_attn's softmax runs in the exp2 domain.
#define QSCALE 0.18033688011112042f   // 0.125 * log2(e)
__global__ __launch_bounds__(256) void latup(
        const float* __restrict__ qproj, const float* __restrict__ klat,
        const float* __restrict__ vlat,
        const unsigned short* __restrict__ wkub, const unsigned short* __restrict__ wvub,
        unsigned short* __restrict__ qb, unsigned short* __restrict__ kb,
        unsigned short* __restrict__ vt) {
    __shared__ __attribute__((aligned(16))) unsigned short ksh[4][16][72];
    __shared__ __attribute__((aligned(16))) unsigned short qsh[4][16][72];
    __shared__ __attribute__((aligned(16))) unsigned short vsh[4][64][24];

    const int bh = blockIdx.y, b = bh >> 4, h = bh & 15;
    const int tid = threadIdx.x, w = tid >> 6, lane = tid & 63;
    const int quad = lane >> 4, l16 = lane & 15;
    const int tw = blockIdx.x * 64 + w * 16;   // wave's 16-token base
    const int t  = tw + l16;

    // B-frags (latents): row = token(l16), k = quad*8..+7 — 128 B/token across 4 lanes
    const float* klp = klat + ((size_t)(b*TSEQ + t))*(NHEAD*DLAT) + h*DLAT + quad*8;
    const float* vlp = vlat + ((size_t)(b*TSEQ + t))*(NHEAD*DLAT) + h*DLAT + quad*8;
    float4 kA = *(const float4*)klp, kB = *(const float4*)(klp + 4);
    float4 vA = *(const float4*)vlp, vB = *(const float4*)(vlp + 4);

    // A-frags (Wku/Wvu bf16): row = dim(c*16+l16), k = quad*8..+7
    bf16x8 xk[4], xv[4];
    #pragma unroll
    for (int c = 0; c < 4; ++c) {
        xk[c] = *(const bf16x8*)&wkub[(c*16 + l16)*DLAT + quad*8];
        xv[c] = *(const bf16x8*)&wvub[(c*16 + l16)*DLAT + quad*8];
    }

    union { bf16x8 v; unsigned u[4]; } yk, yv;
    yk.u[0] = pk2(kA.x, kA.y); yk.u[1] = pk2(kA.z, kA.w);
    yk.u[2] = pk2(kB.x, kB.y); yk.u[3] = pk2(kB.z, kB.w);
    yv.u[0] = pk2(vA.x, vA.y); yv.u[1] = pk2(vA.z, vA.w);
    yv.u[2] = pk2(vB.x, vB.y); yv.u[3] = pk2(vB.z, vB.w);

    f32x4 aK[4], aV[4];
    #pragma unroll
    for (int c = 0; c < 4; ++c) {
        f32x4 z = {0.f, 0.f, 0.f, 0.f};
        aK[c] = __builtin_amdgcn_mfma_f32_16x16x32_bf16(xk[c], yk.v, z, 0, 0, 0);
        aV[c] = __builtin_amdgcn_mfma_f32_16x16x32_bf16(xv[c], yv.v, z, 0, 0, 0);
    }

    // angles: dim d = (c&1)*16 + quad*4 + j, freq idx = d&31 — only 8 distinct/thread
    float C0[4], S0[4], C1[4], S1[4];
    const float tf = (float)t;
    #pragma unroll
    for (int j = 0; j < 4; ++j) {
        float f0 = (float)(quad*4 + j);
        __sincosf(tf * __expf(-f0 * 0.28782313662425572f),          &S0[j], &C0[j]);
        __sincosf(tf * __expf(-(f0 + 16.f) * 0.28782313662425572f), &S1[j], &C1[j]);
    }

    const float* qrow = qproj + ((size_t)(b*TSEQ + t))*CDIM + h*DHEAD;
    #pragma unroll
    for (int c = 0; c < 4; ++c) {
        const float* Cs = (c & 1) ? C1 : C0;
        const float* Ss = (c & 1) ? S1 : S0;
        float a0 = aK[c][0], a1 = aK[c][1], a2 = aK[c][2], a3 = aK[c][3];
        unsigned kw0 = pk2(a0*Cs[0] - a1*Ss[0], a1*Cs[1] + a0*Ss[1]);
        unsigned kw1 = pk2(a2*Cs[2] - a3*Ss[2], a3*Cs[3] + a2*Ss[3]);
        *(uint2*)&ksh[w][l16][c*16 + quad*4] = make_uint2(kw0, kw1);

        float4 qv = *(const float4*)(qrow + c*16 + quad*4);
        unsigned qw0 = pk2((qv.x*Cs[0] - qv.y*Ss[0])*QSCALE, (qv.y*Cs[1] + qv.x*Ss[1])*QSCALE);
        unsigned qw1 = pk2((qv.z*Cs[2] - qv.w*Ss[2])*QSCALE, (qv.w*Cs[3] + qv.z*Ss[3])*QSCALE);
        *(uint2*)&qsh[w][l16][c*16 + quad*4] = make_uint2(qw0, qw1);

        vsh[w][c*16 + quad*4 + 0][l16] = f2bf(aV[c][0]);
        vsh[w][c*16 + quad*4 + 1][l16] = f2bf(aV[c][1]);
        vsh[w][c*16 + quad*4 + 2][l16] = f2bf(aV[c][2]);
        vsh[w][c*16 + quad*4 + 3][l16] = f2bf(aV[c][3]);
    }

    // wave-local transpose: lockstep + drain LDS writes (no __syncthreads needed)
    __asm__ __volatile__("s_waitcnt lgkmcnt(0)" ::: "memory");

    const int ro = lane >> 2, co = (lane & 3) * 16;
    size_t go = ((size_t)bh*TSEQ + tw + ro)*DHEAD + co;
    int4 k0o = *(const int4*)&ksh[w][ro][co];
    int4 k1o = *(const int4*)&ksh[w][ro][co + 8];
    *(int4*)&kb[go]     = k0o;
    *(int4*)&kb[go + 8] = k1o;
    int4 q0o = *(const int4*)&qsh[w][ro][co];
    int4 q1o = *(const int4*)&qsh[w][ro][co + 8];
    *(int4*)&qb[go]     = q0o;
    *(int4*)&qb[go + 8] = q1o;

    size_t vo = ((size_t)bh*DHEAD + lane)*TSEQ + tw;
    int4 v0o = *(const int4*)&vsh[w][lane][0];
    int4 v1o = *(const int4*)&vsh[w][lane][8];
    *(int4*)&vt[vo]     = v0o;
    *(int4*)&vt[vo + 8] = v1o;
}

// ---------------- Flash attention: single-qt blocks, 64-token KV tiles ----------------
// R14 = R13 resubmit (container-level infra failure, no counters; kernel audited
// launch-safe: uniform barriers, in-bounds DMA, bijective both-sides swizzle,
// <=128 VGPR at __launch_bounds__(256,4)).
// R13 theory: R6 counters (Mfma 20%, VALU 48%, Occ 18%) = latency-bound at
// 2 waves/SIMD; 64KB LDS + 512-block grid capped residency at 2 blocks/CU.
// Now: one qt per block, 64-token KV tiles, 32KB LDS, 1024 blocks -> 4/CU =
// 16 waves/CU (2x). Inner loop = proven R4 structure halved; K and V^T share
// one 64x64 XOR-swizzle. Heavy blocks (qt=31) dispatch first.
__global__ __launch_bounds__(256, 4) void flash_attn(
        const unsigned short* __restrict__ qb, const unsigned short* __restrict__ kb,
        const unsigned short* __restrict__ vtb, unsigned short* __restrict__ yatt) {
    const int bh = blockIdx.x;                 // 0..31
    const int qt = 31 - (int)blockIdx.y;       // heavy-first
    const int b = bh >> 4, h = bh & 15;

    __shared__ unsigned short Ks[2][64][64];    // 16 KB
    __shared__ unsigned short VTs[2][64][64];   // 16 KB

    const int tid  = threadIdx.x;
    const int wq   = tid >> 6;
    const int lane = tid & 63;
    const int quad = lane >> 4;
    const int l16  = lane & 15;

    const unsigned short* Kbase = kb  + (size_t)bh * TSEQ * DHEAD;
    const unsigned short* Vbase = vtb + (size_t)bh * DHEAD * TSEQ;

    // DMA source lane-mapping: 64x64 tile, phys colblk = log colblk ^ (row&7)
    const int r8  = lane >> 3;                 // row within 8-row group
    const int c8  = lane & 7;                  // phys col-block (8 elems)
    const int scl = (c8 ^ r8) * 8;             // logical elem offset in row

    // MFMA read offsets (row&7 = l16&7 on the read side)
    const int kx0 = (quad ^ (l16 & 7)) * 8;
    const int kx1 = ((quad + 4) ^ (l16 & 7)) * 8;
    const int vq = (quad >> 1), vodd = (quad & 1) * 4;

    const int n64 = qt + 1;                    // KV 64-tiles (causal: exact cover)

    const unsigned short* qbase =
        qb + ((size_t)bh*TSEQ + qt*64 + wq*16 + l16) * DHEAD + quad*8;
    bf16x8 q0 = *(const bf16x8*)qbase;
    bf16x8 q1 = *(const bf16x8*)(qbase + 32);

    f32x4 oacc[4] = {};
    float m_run = -1e30f, l_run = 0.f;

    #pragma unroll
    for (int i = 0; i < 2; ++i) {   // preload tile 0 into buf 0
        gld_lds16(Kbase + (size_t)(wq*16 + i*8 + r8)*DHEAD + scl,
                  &Ks[0][wq*16 + i*8][0]);
        gld_lds16(Vbase + (size_t)(wq*16 + i*8 + r8)*TSEQ + scl,
                  &VTs[0][wq*16 + i*8][0]);
    }
    __syncthreads();

    for (int j = 0; j < n64; ++j) {
        const int buf = j & 1;
        if (j + 1 < n64) {   // async DMA prefetch of next tile into buf^1
            const int kc = (j + 1) * 64;
            #pragma unroll
            for (int i = 0; i < 2; ++i) {
                gld_lds16(Kbase + (size_t)(kc + wq*16 + i*8 + r8)*DHEAD + scl,
                          &Ks[buf^1][wq*16 + i*8][0]);
                gld_lds16(Vbase + (size_t)(wq*16 + i*8 + r8)*TSEQ + kc + scl,
                          &VTs[buf^1][wq*16 + i*8][0]);
            }
        }

        // S^T = K Q^T (4 chunks of 16 K-rows), log2 units
        f32x4 s[4];
        __builtin_amdgcn_s_setprio(1);
        #pragma unroll
        for (int c = 0; c < 4; ++c) {
            bf16x8 ak0 = *(const bf16x8*)&Ks[buf][c*16 + l16][kx0];
            bf16x8 ak1 = *(const bf16x8*)&Ks[buf][c*16 + l16][kx1];
            f32x4 z = {0.f, 0.f, 0.f, 0.f};
            z = __builtin_amdgcn_mfma_f32_16x16x32_bf16(ak0, q0, z, 0, 0, 0);
            z = __builtin_amdgcn_mfma_f32_16x16x32_bf16(ak1, q1, z, 0, 0, 0);
            s[c] = z;
        }
        __builtin_amdgcn_s_setprio(0);

        if (j == n64 - 1) {   // diagonal tile: causal mask (tile-local compare)
            #pragma unroll
            for (int c = 0; c < 4; ++c)
                #pragma unroll
                for (int r = 0; r < 4; ++r)
                    if (c*16 + quad*4 + r > wq*16 + l16)
                        s[c][r] = -1e30f;
        }

        // online softmax (defer-max, exp2 domain)
        float mx = -1e30f;
        #pragma unroll
        for (int c = 0; c < 4; ++c)
            #pragma unroll
            for (int r = 0; r < 4; ++r) mx = fmaxf(mx, s[c][r]);
        mx = fmaxf(mx, __shfl_xor(mx, 16, 64));
        mx = fmaxf(mx, __shfl_xor(mx, 32, 64));
        if (!__all(mx <= m_run + 8.f)) {
            float mn = fmaxf(m_run, mx);
            float alpha = __builtin_exp2f(m_run - mn);
            m_run = mn;
            l_run *= alpha;
            #pragma unroll
            for (int c = 0; c < 4; ++c)
                #pragma unroll
                for (int r = 0; r < 4; ++r) oacc[c][r] *= alpha;
        }
        float ls = 0.f;
        #pragma unroll
        for (int c = 0; c < 4; ++c)
            #pragma unroll
            for (int r = 0; r < 4; ++r) {
                float p = __builtin_exp2f(s[c][r] - m_run);
                s[c][r] = p;
                ls += p;
            }
        ls += __shfl_xor(ls, 16, 64);
        ls += __shfl_xor(ls, 32, 64);
        l_run += ls;

        // PV: B-frag = packed P (k=quad*4+e matches 16x16x16), A = swizzled V^T
        __builtin_amdgcn_s_setprio(1);
        #pragma unroll
        for (int c = 0; c < 4; ++c) {
            union { bf16x4 v; unsigned u[2]; } bP;
            bP.u[0] = pack_trunc(s[c][1], s[c][0]);
            bP.u[1] = pack_trunc(s[c][3], s[c][2]);
            const int vcol = ((2*c + vq) ^ (l16 & 7)) * 8 + vodd;
            #pragma unroll
            for (int dc = 0; dc < 4; ++dc) {
                bf16x4 av = *(const bf16x4*)&VTs[buf][dc*16 + l16][vcol];
                oacc[dc] = mfma_16x16x16_bf16(av, bP.v, oacc[dc]);
            }
        }
        __builtin_amdgcn_s_setprio(0);

        __syncthreads();   // drains prefetch DMA + protects buf reuse
    }

    // epilogue: O^T -> O via per-wave LDS slab (stride 72), coalesced 16B stores
    float invl = 1.0f / l_run;
    unsigned short* Wt = &Ks[0][0][0] + wq * (16*72);
    #pragma unroll
    for (int c = 0; c < 4; ++c)
        #pragma unroll
        for (int r = 0; r < 4; ++r)
            Wt[(size_t)l16*72 + c*16 + quad*4 + r] = f2bf(oacc[c][r] * invl);
    __asm__ __volatile__("" ::: "memory");
    #pragma unroll
    for (int p = 0; p < 2; ++p) {
        int row = p*8 + (lane >> 3);
        int d0 = (lane & 7) * 8;
        int4 val = *(const int4*)&Wt[row*72 + d0];
        int tg = qt*64 + wq*16 + row;
        *(int4*)&yatt[((size_t)(b*TSEQ + tg))*CDIM + h*DHEAD + d0] = val;
    }
}

extern "C" void kernel_launch(void* const* d_in, const int* in_sizes, int n_in,
                              void* d_out, int out_size, void* d_ws, size_t ws_size,
                              hipStream_t stream) {
    const float* x   = (const float*)d_in[0];
    const float* Wq  = (const float*)d_in[1];
    const float* Wk  = (const float*)d_in[2];
    const float* Wv  = (const float*)d_in[3];
    const float* Wku = (const float*)d_in[4];
    const float* Wvu = (const float*)d_in[5];
    const float* Wc  = (const float*)d_in[6];

    float* out_y  = (float*)d_out;
    float* out_kl = out_y  + (size_t)MROWS * CDIM;
    float* out_vl = out_kl + (size_t)MROWS * NHEAD*DLAT;

    float* qproj = (float*)d_ws;                                           // 16 MB fp32
    unsigned short* xb   = (unsigned short*)(qproj + (size_t)MROWS*CDIM);  // 8 MB
    unsigned short* qb   = xb  + (size_t)MROWS*CDIM;                       // 8 MB
    unsigned short* kb   = qb  + (size_t)MROWS*CDIM;                       // 8 MB
    unsigned short* vt   = kb  + (size_t)MROWS*CDIM;                       // 8 MB
    unsigned short* wall = vt  + (size_t)MROWS*CDIM;                       // [Wq;Wk;Wv;Wc;Wku;Wvu]
    unsigned short* wcb  = wall + (size_t)2048*CDIM;
    unsigned short* wkub = wall + 3145728;
    unsigned short* wvub = wall + 3147776;
    unsigned short* yatt = (unsigned short*)qproj;   // alias: qproj dead after latup

    cvt_all<<<7172, 256, 0, stream>>>(x, Wq, Wk, Wv, Wc, Wku, Wvu, xb, wall);

    gemm_proj<<<dim3(2048/128, MROWS/128), 512, 0, stream>>>(
        xb, wall, qproj, out_kl, out_vl, CDIM);

    latup<<<dim3(TSEQ/64, NBATCH*NHEAD), 256, 0, stream>>>(
        qproj, out_kl, out_vl, wkub, wvub, qb, kb, vt);

    flash_attn<<<dim3(NBATCH*NHEAD, 32), 256, 0, stream>>>(qb, kb, vt, yatt);

    gemm_out<<<dim3(CDIM/128, MROWS/128), 512, 0, stream>>>(yatt, wcb, out_y, CDIM, CDIM);
}

// Round 9
// 194.552 us; speedup vs baseline: 1.0293x; 1.0293x over previous
//
#include <hip/hip_runtime.h>
#include <math.h>

#define NHEAD  16
#define DHEAD  64
#define DLAT   32
#define TSEQ   2048
#define NBATCH 2
#define CDIM   1024
#define MROWS  (NBATCH*TSEQ)   // 4096

typedef __attribute__((ext_vector_type(8))) short bf16x8;
typedef __attribute__((ext_vector_type(4))) short bf16x4;
typedef __attribute__((ext_vector_type(4))) float f32x4;

#define AS1 __attribute__((address_space(1)))
#define AS3 __attribute__((address_space(3)))

__device__ __forceinline__ unsigned short f2bf(float f) {
    union { float f; unsigned u; } v; v.f = f;
    unsigned r = v.u + 0x7fff + ((v.u >> 16) & 1);   // RNE
    return (unsigned short)(r >> 16);
}

// pack two floats -> bf16 pair (RNE), lo | hi<<16
__device__ __forceinline__ unsigned pk2(float lo, float hi) {
    return (unsigned)f2bf(lo) | ((unsigned)f2bf(hi) << 16);
}

// pack bf16(lo)|bf16(hi)<<16 by truncation — one v_perm_b32
__device__ __forceinline__ unsigned pack_trunc(float hi, float lo) {
    return __builtin_amdgcn_perm(__float_as_uint(hi), __float_as_uint(lo), 0x07060302u);
}

__device__ __forceinline__ void gld_lds16(const unsigned short* g, unsigned short* l) {
    __builtin_amdgcn_global_load_lds((const AS1 void*)g, (AS3 void*)l, 16, 0, 0);
}

// 16x16x16 bf16 MFMA: builtin if present, else raw instruction (gfx950 has it)
__device__ __forceinline__ f32x4 mfma_16x16x16_bf16(bf16x4 a, bf16x4 b, f32x4 c) {
#if __has_builtin(__builtin_amdgcn_mfma_f32_16x16x16bf16_1k)
    return __builtin_amdgcn_mfma_f32_16x16x16bf16_1k(a, b, c, 0, 0, 0);
#else
    asm volatile("v_mfma_f32_16x16x16_bf16 %0, %1, %2, %0\n\ts_nop 4"
                 : "+v"(c) : "v"(a), "v"(b));
    return c;
#endif
}

// ---------------- fp32 -> bf16: x and all six weights in ONE launch ----------------
__global__ __launch_bounds__(256) void cvt_all(
        const float* __restrict__ x,  const float* __restrict__ wq,
        const float* __restrict__ wk, const float* __restrict__ wv,
        const float* __restrict__ wc, const float* __restrict__ wku,
        const float* __restrict__ wvu,
        unsigned short* __restrict__ xb, unsigned short* __restrict__ wall) {
    int i = (blockIdx.x * 256 + threadIdx.x) * 4;
    const float* src; unsigned short* dst; int off;
    if      (i < 4194304) { src = x;   dst = xb;             off = 0;       }
    else if (i < 5242880) { src = wq;  dst = wall;           off = 4194304; }
    else if (i < 5767168) { src = wk;  dst = wall + 1048576; off = 5242880; }
    else if (i < 6291456) { src = wv;  dst = wall + 1572864; off = 5767168; }
    else if (i < 7340032) { src = wc;  dst = wall + 2097152; off = 6291456; }
    else if (i < 7342080) { src = wku; dst = wall + 3145728; off = 7340032; }
    else                  { src = wvu; dst = wall + 3147776; off = 7342080; }
    float4 v = *(const float4*)(src + (i - off));
    ushort4 o = { f2bf(v.x), f2bf(v.y), f2bf(v.z), f2bf(v.w) };
    *(ushort4*)(dst + (i - off)) = o;
}

// ---------------- MFMA GEMM core: 128x64 tile, BK=32, 8 waves (512 thr) ----------------
// R15: m102 scaling (TF ~ 70 x waves/CU for the 2-barrier structure) says the
// gemms are still occupancy-starved (proj 16, out 8 waves/CU). BN 128->64:
// proj 1024 blocks -> 4/CU -> 32 waves/CU (max); out 512 -> 2/CU -> 16. Extra
// A re-staging is L2/L3-resident (inputs <= 10 MB). Per-wave 32x32, acc[2][2].
__device__ __forceinline__ void gemm_core(
        const unsigned short* __restrict__ A, const unsigned short* __restrict__ W,
        int K, int bm, int bn, unsigned short* As, unsigned short* Bs,
        f32x4 (&acc)[2][2]) {
    const int tid = threadIdx.x;
    const int w = tid >> 6, lane = tid & 63;
    const int quad = lane >> 4, l16 = lane & 15;
    const int wm = (w >> 1) * 32, wn = (w & 1) * 32;

    // staging: A 128x32 (8KB) by all 512 thr; B 64x32 (4KB) by waves 0-3
    const int sr = tid >> 2;           // A row 0..127
    const int sc = (tid & 3) * 8;      // col elem
    const unsigned short* Ag0 = A + (size_t)(bm + sr) * K + sc;
    const unsigned short* Wg0 = W + (size_t)(bn + sr) * K + sc;   // rows 0..63 used
    unsigned short* AsD = &As[(w*16) * 32];
    unsigned short* BsD = &Bs[(w*16) * 32];

    for (int k0 = 0; k0 < K; k0 += 32) {
        gld_lds16(Ag0 + k0, AsD);
        if (w < 4) gld_lds16(Wg0 + k0, BsD);
        __syncthreads();
        bf16x8 af[2], bf[2];
        #pragma unroll
        for (int t = 0; t < 2; ++t)
            af[t] = *(const bf16x8*)&As[(wm + t*16 + l16)*32 + quad*8];
        #pragma unroll
        for (int c = 0; c < 2; ++c)
            bf[c] = *(const bf16x8*)&Bs[(wn + c*16 + l16)*32 + quad*8];
        #pragma unroll
        for (int t = 0; t < 2; ++t)
            #pragma unroll
            for (int c = 0; c < 2; ++c)
                acc[t][c] = __builtin_amdgcn_mfma_f32_16x16x32_bf16(af[t], bf[c], acc[t][c], 0, 0, 0);
        __syncthreads();
    }
}

__global__ __launch_bounds__(512, 4) void gemm_proj(
        const unsigned short* __restrict__ A, const unsigned short* __restrict__ W,
        float* __restrict__ qproj, float* __restrict__ okl, float* __restrict__ ovl,
        int K) {
    __shared__ unsigned short As[128*32];
    __shared__ unsigned short Bs[64*32];
    const int bm = blockIdx.y * 128, bn = blockIdx.x * 64;
    f32x4 acc[2][2] = {};
    gemm_core(A, W, K, bm, bn, As, Bs, acc);

    const int tid = threadIdx.x;
    const int w = tid >> 6, lane = tid & 63;
    const int quad = lane >> 4, l16 = lane & 15;
    const int wm = (w >> 1) * 32, wn = (w & 1) * 32;

    float* base; int ldo;
    if (bn < 1024)      { base = qproj + bn;        ldo = 1024; }
    else if (bn < 1536) { base = okl + (bn - 1024); ldo = 512;  }
    else                { base = ovl + (bn - 1536); ldo = 512;  }

    #pragma unroll
    for (int t = 0; t < 2; ++t)
        #pragma unroll
        for (int c = 0; c < 2; ++c)
            #pragma unroll
            for (int r = 0; r < 4; ++r) {
                int row = bm + wm + t*16 + quad*4 + r;
                int col = wn + c*16 + l16;
                base[(size_t)row * ldo + col] = acc[t][c][r];
            }
}

__global__ __launch_bounds__(512, 4) void gemm_out(
        const unsigned short* __restrict__ A, const unsigned short* __restrict__ W,
        float* __restrict__ O, int N, int K) {
    __shared__ unsigned short As[128*32];
    __shared__ unsigned short Bs[64*32];
    const int bm = blockIdx.y * 128, bn = blockIdx.x * 64;
    f32x4 acc[2][2] = {};
    gemm_core(A, W, K, bm, bn, As, Bs, acc);

    const int tid = threadIdx.x;
    const int w = tid >> 6, lane = tid & 63;
    const int quad = lane >> 4, l16 = lane & 15;
    const int wm = (w >> 1) * 32, wn = (w & 1) * 32;
    #pragma unroll
    for (int t = 0; t < 2; ++t)
        #pragma unroll
        for (int c = 0; c < 2; ++c)
            #pragma unroll
            for (int r = 0; r < 4; ++r) {
                int row = bm + wm + t*16 + quad*4 + r;
                int col = bn + wn + c*16 + l16;
                O[(size_t)row * N + col] = acc[t][c][r];
            }
}

// ---------------- fused latent up-proj (k,v) via MFMA + q load + RoPE ----------------
// q carries 0.125*log2(e) so flash_attn's softmax runs in the exp2 domain.
#define QSCALE 0.18033688011112042f   // 0.125 * log2(e)
__global__ __launch_bounds__(256) void latup(
        const float* __restrict__ qproj, const float* __restrict__ klat,
        const float* __restrict__ vlat,
        const unsigned short* __restrict__ wkub, const unsigned short* __restrict__ wvub,
        unsigned short* __restrict__ qb, unsigned short* __restrict__ kb,
        unsigned short* __restrict__ vt) {
    __shared__ __attribute__((aligned(16))) unsigned short ksh[4][16][72];
    __shared__ __attribute__((aligned(16))) unsigned short qsh[4][16][72];
    __shared__ __attribute__((aligned(16))) unsigned short vsh[4][64][24];

    const int bh = blockIdx.y, b = bh >> 4, h = bh & 15;
    const int tid = threadIdx.x, w = tid >> 6, lane = tid & 63;
    const int quad = lane >> 4, l16 = lane & 15;
    const int tw = blockIdx.x * 64 + w * 16;   // wave's 16-token base
    const int t  = tw + l16;

    // B-frags (latents): row = token(l16), k = quad*8..+7 — 128 B/token across 4 lanes
    const float* klp = klat + ((size_t)(b*TSEQ + t))*(NHEAD*DLAT) + h*DLAT + quad*8;
    const float* vlp = vlat + ((size_t)(b*TSEQ + t))*(NHEAD*DLAT) + h*DLAT + quad*8;
    float4 kA = *(const float4*)klp, kB = *(const float4*)(klp + 4);
    float4 vA = *(const float4*)vlp, vB = *(const float4*)(vlp + 4);

    // A-frags (Wku/Wvu bf16): row = dim(c*16+l16), k = quad*8..+7
    bf16x8 xk[4], xv[4];
    #pragma unroll
    for (int c = 0; c < 4; ++c) {
        xk[c] = *(const bf16x8*)&wkub[(c*16 + l16)*DLAT + quad*8];
        xv[c] = *(const bf16x8*)&wvub[(c*16 + l16)*DLAT + quad*8];
    }

    union { bf16x8 v; unsigned u[4]; } yk, yv;
    yk.u[0] = pk2(kA.x, kA.y); yk.u[1] = pk2(kA.z, kA.w);
    yk.u[2] = pk2(kB.x, kB.y); yk.u[3] = pk2(kB.z, kB.w);
    yv.u[0] = pk2(vA.x, vA.y); yv.u[1] = pk2(vA.z, vA.w);
    yv.u[2] = pk2(vB.x, vB.y); yv.u[3] = pk2(vB.z, vB.w);

    f32x4 aK[4], aV[4];
    #pragma unroll
    for (int c = 0; c < 4; ++c) {
        f32x4 z = {0.f, 0.f, 0.f, 0.f};
        aK[c] = __builtin_amdgcn_mfma_f32_16x16x32_bf16(xk[c], yk.v, z, 0, 0, 0);
        aV[c] = __builtin_amdgcn_mfma_f32_16x16x32_bf16(xv[c], yv.v, z, 0, 0, 0);
    }

    // angles: dim d = (c&1)*16 + quad*4 + j, freq idx = d&31 — only 8 distinct/thread
    float C0[4], S0[4], C1[4], S1[4];
    const float tf = (float)t;
    #pragma unroll
    for (int j = 0; j < 4; ++j) {
        float f0 = (float)(quad*4 + j);
        __sincosf(tf * __expf(-f0 * 0.28782313662425572f),          &S0[j], &C0[j]);
        __sincosf(tf * __expf(-(f0 + 16.f) * 0.28782313662425572f), &S1[j], &C1[j]);
    }

    const float* qrow = qproj + ((size_t)(b*TSEQ + t))*CDIM + h*DHEAD;
    #pragma unroll
    for (int c = 0; c < 4; ++c) {
        const float* Cs = (c & 1) ? C1 : C0;
        const float* Ss = (c & 1) ? S1 : S0;
        float a0 = aK[c][0], a1 = aK[c][1], a2 = aK[c][2], a3 = aK[c][3];
        unsigned kw0 = pk2(a0*Cs[0] - a1*Ss[0], a1*Cs[1] + a0*Ss[1]);
        unsigned kw1 = pk2(a2*Cs[2] - a3*Ss[2], a3*Cs[3] + a2*Ss[3]);
        *(uint2*)&ksh[w][l16][c*16 + quad*4] = make_uint2(kw0, kw1);

        float4 qv = *(const float4*)(qrow + c*16 + quad*4);
        unsigned qw0 = pk2((qv.x*Cs[0] - qv.y*Ss[0])*QSCALE, (qv.y*Cs[1] + qv.x*Ss[1])*QSCALE);
        unsigned qw1 = pk2((qv.z*Cs[2] - qv.w*Ss[2])*QSCALE, (qv.w*Cs[3] + qv.z*Ss[3])*QSCALE);
        *(uint2*)&qsh[w][l16][c*16 + quad*4] = make_uint2(qw0, qw1);

        vsh[w][c*16 + quad*4 + 0][l16] = f2bf(aV[c][0]);
        vsh[w][c*16 + quad*4 + 1][l16] = f2bf(aV[c][1]);
        vsh[w][c*16 + quad*4 + 2][l16] = f2bf(aV[c][2]);
        vsh[w][c*16 + quad*4 + 3][l16] = f2bf(aV[c][3]);
    }

    // wave-local transpose: lockstep + drain LDS writes (no __syncthreads needed)
    __asm__ __volatile__("s_waitcnt lgkmcnt(0)" ::: "memory");

    const int ro = lane >> 2, co = (lane & 3) * 16;
    size_t go = ((size_t)bh*TSEQ + tw + ro)*DHEAD + co;
    int4 k0o = *(const int4*)&ksh[w][ro][co];
    int4 k1o = *(const int4*)&ksh[w][ro][co + 8];
    *(int4*)&kb[go]     = k0o;
    *(int4*)&kb[go + 8] = k1o;
    int4 q0o = *(const int4*)&qsh[w][ro][co];
    int4 q1o = *(const int4*)&qsh[w][ro][co + 8];
    *(int4*)&qb[go]     = q0o;
    *(int4*)&qb[go + 8] = q1o;

    size_t vo = ((size_t)bh*DHEAD + lane)*TSEQ + tw;
    int4 v0o = *(const int4*)&vsh[w][lane][0];
    int4 v1o = *(const int4*)&vsh[w][lane][8];
    *(int4*)&vt[vo]     = v0o;
    *(int4*)&vt[vo + 8] = v1o;
}

// ---------------- Flash attention: dual-qt co-processing (R6 version, 50.7us) ----------------
// R15: reverted R13/R14's 64-tile single-qt variant (54.6us: halved swizzle
// entropy re-introduced V-read bank conflicts (3.4M->4.4M) and doubled the
// per-token barrier+softmax overhead). This dual-qt 128-tile version is the
// best-measured flash_attn (50.7us). Do not touch.
__device__ __forceinline__ void online_sm(f32x4 (&s)[8], float& m_run, float& l_run,
                                          f32x4 (&o)[4]) {
    float mx = -1e30f;
    #pragma unroll
    for (int c = 0; c < 8; ++c)
        #pragma unroll
        for (int r = 0; r < 4; ++r) mx = fmaxf(mx, s[c][r]);
    mx = fmaxf(mx, __shfl_xor(mx, 16, 64));
    mx = fmaxf(mx, __shfl_xor(mx, 32, 64));
    if (!__all(mx <= m_run + 8.f)) {   // defer-max: P bounded by 2^8
        float mn = fmaxf(m_run, mx);
        float alpha = __builtin_exp2f(m_run - mn);
        m_run = mn;
        l_run *= alpha;
        #pragma unroll
        for (int c = 0; c < 4; ++c)
            #pragma unroll
            for (int r = 0; r < 4; ++r) o[c][r] *= alpha;
    }
    float ls = 0.f;
    #pragma unroll
    for (int c = 0; c < 8; ++c)
        #pragma unroll
        for (int r = 0; r < 4; ++r) {
            float p = __builtin_exp2f(s[c][r] - m_run);
            s[c][r] = p;
            ls += p;
        }
    ls += __shfl_xor(ls, 16, 64);
    ls += __shfl_xor(ls, 32, 64);
    l_run += ls;
}

__global__ __launch_bounds__(256, 2) void flash_attn(
        const unsigned short* __restrict__ qb, const unsigned short* __restrict__ kb,
        const unsigned short* __restrict__ vtb, unsigned short* __restrict__ yatt) {
    const int bh = blockIdx.x;
    const int b = bh >> 4, h = bh & 15;

    __shared__ unsigned short Ks[2][128][64];    // 32 KB
    __shared__ unsigned short VTs[2][64][128];   // 32 KB

    const int tid  = threadIdx.x;
    const int wq   = tid >> 6;
    const int lane = tid & 63;
    const int quad = lane >> 4;
    const int l16  = lane & 15;

    const unsigned short* Kbase = kb  + (size_t)bh * TSEQ * DHEAD;
    const unsigned short* Vbase = vtb + (size_t)bh * DHEAD * TSEQ;

    // DMA source lane-mapping (swizzled)
    const int kr8 = lane >> 3, kcp = lane & 7;
    const int kcl = (kcp ^ kr8) * 8;              // K logical elem offset in row
    const int vr4 = lane >> 4, vcp = lane & 15;

    // swizzled MFMA read offsets
    const int kx0 = (quad ^ (l16 & 7)) * 8;
    const int kx1 = ((quad + 4) ^ (l16 & 7)) * 8;
    // V^T b64 read: log col8-block = 2c + (quad>>1), +4 elems when quad odd
    const int vq = (quad >> 1), vodd = (quad & 1) * 4;

    const int qtA = blockIdx.y;          // 0..15
    const int qtB = 31 - qtA;            // 16..31
    const int nA  = (qtA + 2) >> 1;      // KV 128-tiles for half A (<= 8)
    const int nB  = (qtB + 2) >> 1;      // KV 128-tiles for half B (>= 9) — loop bound

    const unsigned short* qbaseA =
        qb + ((size_t)bh*TSEQ + qtA*64 + wq*16 + l16) * DHEAD + quad*8;
    const unsigned short* qbaseB =
        qb + ((size_t)bh*TSEQ + qtB*64 + wq*16 + l16) * DHEAD + quad*8;
    bf16x8 qA0 = *(const bf16x8*)qbaseA;
    bf16x8 qA1 = *(const bf16x8*)(qbaseA + 32);
    bf16x8 qB0 = *(const bf16x8*)qbaseB;
    bf16x8 qB1 = *(const bf16x8*)(qbaseB + 32);

    f32x4 oA[4] = {}, oB[4] = {};
    float mA = -1e30f, lA = 0.f;
    float mB = -1e30f, lB = 0.f;

    #pragma unroll
    for (int i = 0; i < 4; ++i) {   // preload tile 0 into buf 0
        gld_lds16(Kbase + (size_t)(wq*32 + i*8 + kr8)*DHEAD + kcl,
                  &Ks[0][wq*32 + i*8][0]);
        int vcl = (vcp ^ ((i*4 + vr4) & 15)) * 8;
        gld_lds16(Vbase + (size_t)(wq*16 + i*4 + vr4)*TSEQ + vcl,
                  &VTs[0][wq*16 + i*4][0]);
    }
    __syncthreads();

    for (int j = 0; j < nB; ++j) {
        const int buf = j & 1;
        if (j + 1 < nB) {   // async DMA prefetch of next tile into buf^1
            const int kc = (j + 1) * 128;
            #pragma unroll
            for (int i = 0; i < 4; ++i) {
                gld_lds16(Kbase + (size_t)(kc + wq*32 + i*8 + kr8)*DHEAD + kcl,
                          &Ks[buf^1][wq*32 + i*8][0]);
                int vcl = (vcp ^ ((i*4 + vr4) & 15)) * 8;
                gld_lds16(Vbase + (size_t)(wq*16 + i*4 + vr4)*TSEQ + kc + vcl,
                          &VTs[buf^1][wq*16 + i*4][0]);
            }
        }
        const bool actA = (j < nA);

        // S^T = K Q^T — shared K frags feed both halves (log2 units)
        f32x4 sA[8], sB[8];
        __builtin_amdgcn_s_setprio(1);
        if (actA) {
            #pragma unroll
            for (int c = 0; c < 8; ++c) {
                bf16x8 ak0 = *(const bf16x8*)&Ks[buf][c*16 + l16][kx0];
                bf16x8 ak1 = *(const bf16x8*)&Ks[buf][c*16 + l16][kx1];
                f32x4 zB = {0.f, 0.f, 0.f, 0.f};
                zB = __builtin_amdgcn_mfma_f32_16x16x32_bf16(ak0, qB0, zB, 0, 0, 0);
                zB = __builtin_amdgcn_mfma_f32_16x16x32_bf16(ak1, qB1, zB, 0, 0, 0);
                sB[c] = zB;
                f32x4 zA = {0.f, 0.f, 0.f, 0.f};
                zA = __builtin_amdgcn_mfma_f32_16x16x32_bf16(ak0, qA0, zA, 0, 0, 0);
                zA = __builtin_amdgcn_mfma_f32_16x16x32_bf16(ak1, qA1, zA, 0, 0, 0);
                sA[c] = zA;
            }
        } else {
            #pragma unroll
            for (int c = 0; c < 8; ++c) {
                bf16x8 ak0 = *(const bf16x8*)&Ks[buf][c*16 + l16][kx0];
                bf16x8 ak1 = *(const bf16x8*)&Ks[buf][c*16 + l16][kx1];
                f32x4 zB = {0.f, 0.f, 0.f, 0.f};
                zB = __builtin_amdgcn_mfma_f32_16x16x32_bf16(ak0, qB0, zB, 0, 0, 0);
                zB = __builtin_amdgcn_mfma_f32_16x16x32_bf16(ak1, qB1, zB, 0, 0, 0);
                sB[c] = zB;
            }
        }
        __builtin_amdgcn_s_setprio(0);

        if (j == nB - 1) {   // causal mask for half B (covers 128-overhang)
            #pragma unroll
            for (int c = 0; c < 8; ++c)
                #pragma unroll
                for (int r = 0; r < 4; ++r)
                    if (j*128 + c*16 + quad*4 + r > qtB*64 + wq*16 + l16)
                        sB[c][r] = -1e30f;
        }
        if (actA && j == nA - 1) {   // causal mask for half A
            #pragma unroll
            for (int c = 0; c < 8; ++c)
                #pragma unroll
                for (int r = 0; r < 4; ++r)
                    if (j*128 + c*16 + quad*4 + r > qtA*64 + wq*16 + l16)
                        sA[c][r] = -1e30f;
        }

        online_sm(sB, mB, lB, oB);
        if (actA) online_sm(sA, mA, lA, oA);

        // PV: shared V frags, B-frag = packed sacc (k=quad*4+e matches 16x16x16)
        __builtin_amdgcn_s_setprio(1);
        if (actA) {
            #pragma unroll
            for (int c = 0; c < 8; ++c) {
                union { bf16x4 v; unsigned u[2]; } bPB, bPA;
                bPB.u[0] = pack_trunc(sB[c][1], sB[c][0]);
                bPB.u[1] = pack_trunc(sB[c][3], sB[c][2]);
                bPA.u[0] = pack_trunc(sA[c][1], sA[c][0]);
                bPA.u[1] = pack_trunc(sA[c][3], sA[c][2]);
                const int vcol = ((2*c + vq) ^ l16) * 8 + vodd;
                #pragma unroll
                for (int dc = 0; dc < 4; ++dc) {
                    bf16x4 av = *(const bf16x4*)&VTs[buf][dc*16 + l16][vcol];
                    oB[dc] = mfma_16x16x16_bf16(av, bPB.v, oB[dc]);
                    oA[dc] = mfma_16x16x16_bf16(av, bPA.v, oA[dc]);
                }
            }
        } else {
            #pragma unroll
            for (int c = 0; c < 8; ++c) {
                union { bf16x4 v; unsigned u[2]; } bPB;
                bPB.u[0] = pack_trunc(sB[c][1], sB[c][0]);
                bPB.u[1] = pack_trunc(sB[c][3], sB[c][2]);
                const int vcol = ((2*c + vq) ^ l16) * 8 + vodd;
                #pragma unroll
                for (int dc = 0; dc < 4; ++dc) {
                    bf16x4 av = *(const bf16x4*)&VTs[buf][dc*16 + l16][vcol];
                    oB[dc] = mfma_16x16x16_bf16(av, bPB.v, oB[dc]);
                }
            }
        }
        __builtin_amdgcn_s_setprio(0);

        __syncthreads();   // drains prefetch DMA + protects buf reuse
    }

    // epilogue: O^T -> O via per-wave LDS scratch; halves use disjoint slabs
    #pragma unroll
    for (int half = 0; half < 2; ++half) {
        const f32x4* o = half ? oB : oA;
        float invl = 1.0f / (half ? lB : lA);
        int qt = half ? qtB : qtA;
        unsigned short* Wt = &Ks[half][0][0] + wq * (16*72);
        #pragma unroll
        for (int c = 0; c < 4; ++c)
            #pragma unroll
            for (int r = 0; r < 4; ++r)
                Wt[(size_t)l16*72 + c*16 + quad*4 + r] = f2bf(o[c][r] * invl);
        __asm__ __volatile__("" ::: "memory");
        #pragma unroll
        for (int p = 0; p < 2; ++p) {
            int row = p*8 + (lane >> 3);
            int d0 = (lane & 7) * 8;
            int4 val = *(const int4*)&Wt[row*72 + d0];
            int tg = qt*64 + wq*16 + row;
            *(int4*)&yatt[((size_t)(b*TSEQ + tg))*CDIM + h*DHEAD + d0] = val;
        }
    }
}

extern "C" void kernel_launch(void* const* d_in, const int* in_sizes, int n_in,
                              void* d_out, int out_size, void* d_ws, size_t ws_size,
                              hipStream_t stream) {
    const float* x   = (const float*)d_in[0];
    const float* Wq  = (const float*)d_in[1];
    const float* Wk  = (const float*)d_in[2];
    const float* Wv  = (const float*)d_in[3];
    const float* Wku = (const float*)d_in[4];
    const float* Wvu = (const float*)d_in[5];
    const float* Wc  = (const float*)d_in[6];

    float* out_y  = (float*)d_out;
    float* out_kl = out_y  + (size_t)MROWS * CDIM;
    float* out_vl = out_kl + (size_t)MROWS * NHEAD*DLAT;

    float* qproj = (float*)d_ws;                                           // 16 MB fp32
    unsigned short* xb   = (unsigned short*)(qproj + (size_t)MROWS*CDIM);  // 8 MB
    unsigned short* qb   = xb  + (size_t)MROWS*CDIM;                       // 8 MB
    unsigned short* kb   = qb  + (size_t)MROWS*CDIM;                       // 8 MB
    unsigned short* vt   = kb  + (size_t)MROWS*CDIM;                       // 8 MB
    unsigned short* wall = vt  + (size_t)MROWS*CDIM;                       // [Wq;Wk;Wv;Wc;Wku;Wvu]
    unsigned short* wcb  = wall + (size_t)2048*CDIM;
    unsigned short* wkub = wall + 3145728;
    unsigned short* wvub = wall + 3147776;
    unsigned short* yatt = (unsigned short*)qproj;   // alias: qproj dead after latup

    cvt_all<<<7172, 256, 0, stream>>>(x, Wq, Wk, Wv, Wc, Wku, Wvu, xb, wall);

    gemm_proj<<<dim3(2048/64, MROWS/128), 512, 0, stream>>>(
        xb, wall, qproj, out_kl, out_vl, CDIM);

    latup<<<dim3(TSEQ/64, NBATCH*NHEAD), 256, 0, stream>>>(
        qproj, out_kl, out_vl, wkub, wvub, qb, kb, vt);

    flash_attn<<<dim3(NBATCH*NHEAD, 16), 256, 0, stream>>>(qb, kb, vt, yatt);

    gemm_out<<<dim3(CDIM/64, MROWS/128), 512, 0, stream>>>(yatt, wcb, out_y, CDIM, CDIM);
}

// Round 10
// 191.637 us; speedup vs baseline: 1.0450x; 1.0152x over previous
//
#include <hip/hip_runtime.h>
#include <math.h>

#define NHEAD  16
#define DHEAD  64
#define DLAT   32
#define TSEQ   2048
#define NBATCH 2
#define CDIM   1024
#define MROWS  (NBATCH*TSEQ)   // 4096

typedef __attribute__((ext_vector_type(8))) short bf16x8;
typedef __attribute__((ext_vector_type(4))) short bf16x4;
typedef __attribute__((ext_vector_type(4))) float f32x4;

#define AS1 __attribute__((address_space(1)))
#define AS3 __attribute__((address_space(3)))

__device__ __forceinline__ unsigned short f2bf(float f) {
    union { float f; unsigned u; } v; v.f = f;
    unsigned r = v.u + 0x7fff + ((v.u >> 16) & 1);   // RNE
    return (unsigned short)(r >> 16);
}

// pack two floats -> bf16 pair (RNE), lo | hi<<16
__device__ __forceinline__ unsigned pk2(float lo, float hi) {
    return (unsigned)f2bf(lo) | ((unsigned)f2bf(hi) << 16);
}

// pack bf16(lo)|bf16(hi)<<16 by truncation — one v_perm_b32
__device__ __forceinline__ unsigned pack_trunc(float hi, float lo) {
    return __builtin_amdgcn_perm(__float_as_uint(hi), __float_as_uint(lo), 0x07060302u);
}

__device__ __forceinline__ void gld_lds16(const unsigned short* g, unsigned short* l) {
    __builtin_amdgcn_global_load_lds((const AS1 void*)g, (AS3 void*)l, 16, 0, 0);
}

// 16x16x16 bf16 MFMA: builtin if present, else raw instruction (gfx950 has it)
__device__ __forceinline__ f32x4 mfma_16x16x16_bf16(bf16x4 a, bf16x4 b, f32x4 c) {
#if __has_builtin(__builtin_amdgcn_mfma_f32_16x16x16bf16_1k)
    return __builtin_amdgcn_mfma_f32_16x16x16bf16_1k(a, b, c, 0, 0, 0);
#else
    asm volatile("v_mfma_f32_16x16x16_bf16 %0, %1, %2, %0\n\ts_nop 4"
                 : "+v"(c) : "v"(a), "v"(b));
    return c;
#endif
}

// ---------------- fp32 -> bf16: x and all six weights in ONE launch ----------------
__global__ __launch_bounds__(256) void cvt_all(
        const float* __restrict__ x,  const float* __restrict__ wq,
        const float* __restrict__ wk, const float* __restrict__ wv,
        const float* __restrict__ wc, const float* __restrict__ wku,
        const float* __restrict__ wvu,
        unsigned short* __restrict__ xb, unsigned short* __restrict__ wall) {
    int i = (blockIdx.x * 256 + threadIdx.x) * 4;
    const float* src; unsigned short* dst; int off;
    if      (i < 4194304) { src = x;   dst = xb;             off = 0;       }
    else if (i < 5242880) { src = wq;  dst = wall;           off = 4194304; }
    else if (i < 5767168) { src = wk;  dst = wall + 1048576; off = 5242880; }
    else if (i < 6291456) { src = wv;  dst = wall + 1572864; off = 5767168; }
    else if (i < 7340032) { src = wc;  dst = wall + 2097152; off = 6291456; }
    else if (i < 7342080) { src = wku; dst = wall + 3145728; off = 7340032; }
    else                  { src = wvu; dst = wall + 3147776; off = 7342080; }
    float4 v = *(const float4*)(src + (i - off));
    ushort4 o = { f2bf(v.x), f2bf(v.y), f2bf(v.z), f2bf(v.w) };
    *(ushort4*)(dst + (i - off)) = o;
}

// ---------------- MFMA GEMM core: 128x64 tile, BK=32, 8 waves (512 thr) ----------------
// R15 (kept): BN=64 doubled blocks/CU for both gemms — measured win in R9.
__device__ __forceinline__ void gemm_core(
        const unsigned short* __restrict__ A, const unsigned short* __restrict__ W,
        int K, int bm, int bn, unsigned short* As, unsigned short* Bs,
        f32x4 (&acc)[2][2]) {
    const int tid = threadIdx.x;
    const int w = tid >> 6, lane = tid & 63;
    const int quad = lane >> 4, l16 = lane & 15;
    const int wm = (w >> 1) * 32, wn = (w & 1) * 32;

    // staging: A 128x32 (8KB) by all 512 thr; B 64x32 (4KB) by waves 0-3
    const int sr = tid >> 2;           // A row 0..127
    const int sc = (tid & 3) * 8;      // col elem
    const unsigned short* Ag0 = A + (size_t)(bm + sr) * K + sc;
    const unsigned short* Wg0 = W + (size_t)(bn + sr) * K + sc;   // rows 0..63 used
    unsigned short* AsD = &As[(w*16) * 32];
    unsigned short* BsD = &Bs[(w*16) * 32];

    for (int k0 = 0; k0 < K; k0 += 32) {
        gld_lds16(Ag0 + k0, AsD);
        if (w < 4) gld_lds16(Wg0 + k0, BsD);
        __syncthreads();
        bf16x8 af[2], bf[2];
        #pragma unroll
        for (int t = 0; t < 2; ++t)
            af[t] = *(const bf16x8*)&As[(wm + t*16 + l16)*32 + quad*8];
        #pragma unroll
        for (int c = 0; c < 2; ++c)
            bf[c] = *(const bf16x8*)&Bs[(wn + c*16 + l16)*32 + quad*8];
        #pragma unroll
        for (int t = 0; t < 2; ++t)
            #pragma unroll
            for (int c = 0; c < 2; ++c)
                acc[t][c] = __builtin_amdgcn_mfma_f32_16x16x32_bf16(af[t], bf[c], acc[t][c], 0, 0, 0);
        __syncthreads();
    }
}

__global__ __launch_bounds__(512, 4) void gemm_proj(
        const unsigned short* __restrict__ A, const unsigned short* __restrict__ W,
        float* __restrict__ qproj, float* __restrict__ okl, float* __restrict__ ovl,
        int K) {
    __shared__ unsigned short As[128*32];
    __shared__ unsigned short Bs[64*32];
    const int bm = blockIdx.y * 128, bn = blockIdx.x * 64;
    f32x4 acc[2][2] = {};
    gemm_core(A, W, K, bm, bn, As, Bs, acc);

    const int tid = threadIdx.x;
    const int w = tid >> 6, lane = tid & 63;
    const int quad = lane >> 4, l16 = lane & 15;
    const int wm = (w >> 1) * 32, wn = (w & 1) * 32;

    float* base; int ldo;
    if (bn < 1024)      { base = qproj + bn;        ldo = 1024; }
    else if (bn < 1536) { base = okl + (bn - 1024); ldo = 512;  }
    else                { base = ovl + (bn - 1536); ldo = 512;  }

    #pragma unroll
    for (int t = 0; t < 2; ++t)
        #pragma unroll
        for (int c = 0; c < 2; ++c)
            #pragma unroll
            for (int r = 0; r < 4; ++r) {
                int row = bm + wm + t*16 + quad*4 + r;
                int col = wn + c*16 + l16;
                base[(size_t)row * ldo + col] = acc[t][c][r];
            }
}

__global__ __launch_bounds__(512, 4) void gemm_out(
        const unsigned short* __restrict__ A, const unsigned short* __restrict__ W,
        float* __restrict__ O, int N, int K) {
    __shared__ unsigned short As[128*32];
    __shared__ unsigned short Bs[64*32];
    const int bm = blockIdx.y * 128, bn = blockIdx.x * 64;
    f32x4 acc[2][2] = {};
    gemm_core(A, W, K, bm, bn, As, Bs, acc);

    const int tid = threadIdx.x;
    const int w = tid >> 6, lane = tid & 63;
    const int quad = lane >> 4, l16 = lane & 15;
    const int wm = (w >> 1) * 32, wn = (w & 1) * 32;
    #pragma unroll
    for (int t = 0; t < 2; ++t)
        #pragma unroll
        for (int c = 0; c < 2; ++c)
            #pragma unroll
            for (int r = 0; r < 4; ++r) {
                int row = bm + wm + t*16 + quad*4 + r;
                int col = bn + wn + c*16 + l16;
                O[(size_t)row * N + col] = acc[t][c][r];
            }
}

// ---------------- fused latent up-proj (k,v) via MFMA + q load + RoPE ----------------
// q carries 0.125*log2(e) so flash_attn's softmax runs in the exp2 domain.
#define QSCALE 0.18033688011112042f   // 0.125 * log2(e)
__global__ __launch_bounds__(256) void latup(
        const float* __restrict__ qproj, const float* __restrict__ klat,
        const float* __restrict__ vlat,
        const unsigned short* __restrict__ wkub, const unsigned short* __restrict__ wvub,
        unsigned short* __restrict__ qb, unsigned short* __restrict__ kb,
        unsigned short* __restrict__ vt) {
    __shared__ __attribute__((aligned(16))) unsigned short ksh[4][16][72];
    __shared__ __attribute__((aligned(16))) unsigned short qsh[4][16][72];
    __shared__ __attribute__((aligned(16))) unsigned short vsh[4][64][24];

    const int bh = blockIdx.y, b = bh >> 4, h = bh & 15;
    const int tid = threadIdx.x, w = tid >> 6, lane = tid & 63;
    const int quad = lane >> 4, l16 = lane & 15;
    const int tw = blockIdx.x * 64 + w * 16;   // wave's 16-token base
    const int t  = tw + l16;

    // B-frags (latents): row = token(l16), k = quad*8..+7 — 128 B/token across 4 lanes
    const float* klp = klat + ((size_t)(b*TSEQ + t))*(NHEAD*DLAT) + h*DLAT + quad*8;
    const float* vlp = vlat + ((size_t)(b*TSEQ + t))*(NHEAD*DLAT) + h*DLAT + quad*8;
    float4 kA = *(const float4*)klp, kB = *(const float4*)(klp + 4);
    float4 vA = *(const float4*)vlp, vB = *(const float4*)(vlp + 4);

    // A-frags (Wku/Wvu bf16): row = dim(c*16+l16), k = quad*8..+7
    bf16x8 xk[4], xv[4];
    #pragma unroll
    for (int c = 0; c < 4; ++c) {
        xk[c] = *(const bf16x8*)&wkub[(c*16 + l16)*DLAT + quad*8];
        xv[c] = *(const bf16x8*)&wvub[(c*16 + l16)*DLAT + quad*8];
    }

    union { bf16x8 v; unsigned u[4]; } yk, yv;
    yk.u[0] = pk2(kA.x, kA.y); yk.u[1] = pk2(kA.z, kA.w);
    yk.u[2] = pk2(kB.x, kB.y); yk.u[3] = pk2(kB.z, kB.w);
    yv.u[0] = pk2(vA.x, vA.y); yv.u[1] = pk2(vA.z, vA.w);
    yv.u[2] = pk2(vB.x, vB.y); yv.u[3] = pk2(vB.z, vB.w);

    f32x4 aK[4], aV[4];
    #pragma unroll
    for (int c = 0; c < 4; ++c) {
        f32x4 z = {0.f, 0.f, 0.f, 0.f};
        aK[c] = __builtin_amdgcn_mfma_f32_16x16x32_bf16(xk[c], yk.v, z, 0, 0, 0);
        aV[c] = __builtin_amdgcn_mfma_f32_16x16x32_bf16(xv[c], yv.v, z, 0, 0, 0);
    }

    // angles: dim d = (c&1)*16 + quad*4 + j, freq idx = d&31 — only 8 distinct/thread
    float C0[4], S0[4], C1[4], S1[4];
    const float tf = (float)t;
    #pragma unroll
    for (int j = 0; j < 4; ++j) {
        float f0 = (float)(quad*4 + j);
        __sincosf(tf * __expf(-f0 * 0.28782313662425572f),          &S0[j], &C0[j]);
        __sincosf(tf * __expf(-(f0 + 16.f) * 0.28782313662425572f), &S1[j], &C1[j]);
    }

    const float* qrow = qproj + ((size_t)(b*TSEQ + t))*CDIM + h*DHEAD;
    #pragma unroll
    for (int c = 0; c < 4; ++c) {
        const float* Cs = (c & 1) ? C1 : C0;
        const float* Ss = (c & 1) ? S1 : S0;
        float a0 = aK[c][0], a1 = aK[c][1], a2 = aK[c][2], a3 = aK[c][3];
        unsigned kw0 = pk2(a0*Cs[0] - a1*Ss[0], a1*Cs[1] + a0*Ss[1]);
        unsigned kw1 = pk2(a2*Cs[2] - a3*Ss[2], a3*Cs[3] + a2*Ss[3]);
        *(uint2*)&ksh[w][l16][c*16 + quad*4] = make_uint2(kw0, kw1);

        float4 qv = *(const float4*)(qrow + c*16 + quad*4);
        unsigned qw0 = pk2((qv.x*Cs[0] - qv.y*Ss[0])*QSCALE, (qv.y*Cs[1] + qv.x*Ss[1])*QSCALE);
        unsigned qw1 = pk2((qv.z*Cs[2] - qv.w*Ss[2])*QSCALE, (qv.w*Cs[3] + qv.z*Ss[3])*QSCALE);
        *(uint2*)&qsh[w][l16][c*16 + quad*4] = make_uint2(qw0, qw1);

        vsh[w][c*16 + quad*4 + 0][l16] = f2bf(aV[c][0]);
        vsh[w][c*16 + quad*4 + 1][l16] = f2bf(aV[c][1]);
        vsh[w][c*16 + quad*4 + 2][l16] = f2bf(aV[c][2]);
        vsh[w][c*16 + quad*4 + 3][l16] = f2bf(aV[c][3]);
    }

    // wave-local transpose: lockstep + drain LDS writes (no __syncthreads needed)
    __asm__ __volatile__("s_waitcnt lgkmcnt(0)" ::: "memory");

    const int ro = lane >> 2, co = (lane & 3) * 16;
    size_t go = ((size_t)bh*TSEQ + tw + ro)*DHEAD + co;
    int4 k0o = *(const int4*)&ksh[w][ro][co];
    int4 k1o = *(const int4*)&ksh[w][ro][co + 8];
    *(int4*)&kb[go]     = k0o;
    *(int4*)&kb[go + 8] = k1o;
    int4 q0o = *(const int4*)&qsh[w][ro][co];
    int4 q1o = *(const int4*)&qsh[w][ro][co + 8];
    *(int4*)&qb[go]     = q0o;
    *(int4*)&qb[go + 8] = q1o;

    size_t vo = ((size_t)bh*DHEAD + lane)*TSEQ + tw;
    int4 v0o = *(const int4*)&vsh[w][lane][0];
    int4 v1o = *(const int4*)&vsh[w][lane][8];
    *(int4*)&vt[vo]     = v0o;
    *(int4*)&vt[vo + 8] = v1o;
}

// ---------------- Flash attention: 8-wave blocks, wave-split qt pair ----------------
// R16: R9 showed identical flash source at 50.7us (R6) and 64.2us (R9) — ~25%
// container/clock variance; structure comparisons only. This round pulls the
// occupancy lever WITHOUT shrinking the tile (R8's mistake): same 128-token KV
// tile, same swizzles, same inner loop, but 512 threads — waves 0-3 own qtA,
// waves 4-7 own qtB (was register-level dual-qt in 4 waves). Identical total
// work and barrier count; 16 waves/CU (was 8) so other waves' MFMAs hide each
// wave's serial softmax chain (m114 TLP mechanism). Light waves keep staging
// their K/V rows while compute-idle (prefetch outside the per-wave guard).
__device__ __forceinline__ void online_sm(f32x4 (&s)[8], float& m_run, float& l_run,
                                          f32x4 (&o)[4]) {
    float mx = -1e30f;
    #pragma unroll
    for (int c = 0; c < 8; ++c)
        #pragma unroll
        for (int r = 0; r < 4; ++r) mx = fmaxf(mx, s[c][r]);
    mx = fmaxf(mx, __shfl_xor(mx, 16, 64));
    mx = fmaxf(mx, __shfl_xor(mx, 32, 64));
    if (!__all(mx <= m_run + 8.f)) {   // defer-max: P bounded by 2^8
        float mn = fmaxf(m_run, mx);
        float alpha = __builtin_exp2f(m_run - mn);
        m_run = mn;
        l_run *= alpha;
        #pragma unroll
        for (int c = 0; c < 4; ++c)
            #pragma unroll
            for (int r = 0; r < 4; ++r) o[c][r] *= alpha;
    }
    float ls = 0.f;
    #pragma unroll
    for (int c = 0; c < 8; ++c)
        #pragma unroll
        for (int r = 0; r < 4; ++r) {
            float p = __builtin_exp2f(s[c][r] - m_run);
            s[c][r] = p;
            ls += p;
        }
    ls += __shfl_xor(ls, 16, 64);
    ls += __shfl_xor(ls, 32, 64);
    l_run += ls;
}

__global__ __launch_bounds__(512, 4) void flash_attn(
        const unsigned short* __restrict__ qb, const unsigned short* __restrict__ kb,
        const unsigned short* __restrict__ vtb, unsigned short* __restrict__ yatt) {
    const int bh = blockIdx.x;
    const int b = bh >> 4, h = bh & 15;

    __shared__ unsigned short Ks[2][128][64];    // 32 KB
    __shared__ unsigned short VTs[2][64][128];   // 32 KB

    const int tid  = threadIdx.x;
    const int w    = tid >> 6;          // 0..7
    const int lane = tid & 63;
    const int quad = lane >> 4;
    const int l16  = lane & 15;
    const bool heavy = (w >= 4);
    const int wq = w & 3;               // 16-row group within this wave's half

    const int qtA = blockIdx.y;          // 0..15 (light half)
    const int qtB = 31 - qtA;            // 16..31 (heavy half)
    const int qt  = heavy ? qtB : qtA;
    const int myN = (qt + 2) >> 1;       // KV 128-tiles this wave computes
    const int nB  = (qtB + 2) >> 1;      // loop bound (heavy side)

    const unsigned short* Kbase = kb  + (size_t)bh * TSEQ * DHEAD;
    const unsigned short* Vbase = vtb + (size_t)bh * DHEAD * TSEQ;

    // K DMA: wave w stages tile rows [w*16, w*16+16) — 2 issues x 8 rows
    const int kr8 = lane >> 3, kc8 = lane & 7;
    const int kcl = (kc8 ^ kr8) * 8;            // phys colblk = log ^ (row&7)
    // V DMA: wave w stages dim rows [w*8, w*8+8) — 2 issues x 4 rows
    const int vr4 = lane >> 4, vcp = lane & 15; // phys colblk = log ^ (row&15)

    // swizzled MFMA read offsets
    const int kx0 = (quad ^ (l16 & 7)) * 8;
    const int kx1 = ((quad + 4) ^ (l16 & 7)) * 8;
    const int vq = (quad >> 1), vodd = (quad & 1) * 4;

    const unsigned short* qbase =
        qb + ((size_t)bh*TSEQ + qt*64 + wq*16 + l16) * DHEAD + quad*8;
    bf16x8 q0 = *(const bf16x8*)qbase;
    bf16x8 q1 = *(const bf16x8*)(qbase + 32);

    f32x4 oacc[4] = {};
    float m_run = -1e30f, l_run = 0.f;

    #pragma unroll
    for (int i = 0; i < 2; ++i) {   // preload tile 0 into buf 0
        gld_lds16(Kbase + (size_t)(w*16 + i*8 + kr8)*DHEAD + kcl,
                  &Ks[0][w*16 + i*8][0]);
        int vrow = w*8 + i*4 + vr4;
        int vcl = (vcp ^ (vrow & 15)) * 8;
        gld_lds16(Vbase + (size_t)vrow*TSEQ + vcl, &VTs[0][w*8 + i*4][0]);
    }
    __syncthreads();

    for (int j = 0; j < nB; ++j) {
        const int buf = j & 1;
        if (j + 1 < nB) {   // async DMA prefetch of next tile into buf^1 (ALL waves)
            const int kc = (j + 1) * 128;
            #pragma unroll
            for (int i = 0; i < 2; ++i) {
                gld_lds16(Kbase + (size_t)(kc + w*16 + i*8 + kr8)*DHEAD + kcl,
                          &Ks[buf^1][w*16 + i*8][0]);
                int vrow = w*8 + i*4 + vr4;
                int vcl = (vcp ^ (vrow & 15)) * 8;
                gld_lds16(Vbase + (size_t)vrow*TSEQ + kc + vcl,
                          &VTs[buf^1][w*8 + i*4][0]);
            }
        }

        if (j < myN) {   // wave-uniform guard: light waves idle after their range
            // S^T = K Q^T (8 chunks of 16 K-rows), log2 units
            f32x4 s[8];
            __builtin_amdgcn_s_setprio(1);
            #pragma unroll
            for (int c = 0; c < 8; ++c) {
                bf16x8 ak0 = *(const bf16x8*)&Ks[buf][c*16 + l16][kx0];
                bf16x8 ak1 = *(const bf16x8*)&Ks[buf][c*16 + l16][kx1];
                f32x4 z = {0.f, 0.f, 0.f, 0.f};
                z = __builtin_amdgcn_mfma_f32_16x16x32_bf16(ak0, q0, z, 0, 0, 0);
                z = __builtin_amdgcn_mfma_f32_16x16x32_bf16(ak1, q1, z, 0, 0, 0);
                s[c] = z;
            }
            __builtin_amdgcn_s_setprio(0);

            if (j == myN - 1) {   // causal mask (covers the 128-overhang too)
                #pragma unroll
                for (int c = 0; c < 8; ++c)
                    #pragma unroll
                    for (int r = 0; r < 4; ++r)
                        if (j*128 + c*16 + quad*4 + r > qt*64 + wq*16 + l16)
                            s[c][r] = -1e30f;
            }

            online_sm(s, m_run, l_run, oacc);

            // PV: B-frag = packed P (k=quad*4+e matches 16x16x16), A = swizzled V^T
            __builtin_amdgcn_s_setprio(1);
            #pragma unroll
            for (int c = 0; c < 8; ++c) {
                union { bf16x4 v; unsigned u[2]; } bP;
                bP.u[0] = pack_trunc(s[c][1], s[c][0]);
                bP.u[1] = pack_trunc(s[c][3], s[c][2]);
                const int vcol = ((2*c + vq) ^ l16) * 8 + vodd;
                #pragma unroll
                for (int dc = 0; dc < 4; ++dc) {
                    bf16x4 av = *(const bf16x4*)&VTs[buf][dc*16 + l16][vcol];
                    oacc[dc] = mfma_16x16x16_bf16(av, bP.v, oacc[dc]);
                }
            }
            __builtin_amdgcn_s_setprio(0);
        }

        __syncthreads();   // drains prefetch DMA + protects buf reuse (all waves)
    }

    // epilogue: O^T -> O via per-wave LDS slab (stride 72), coalesced 16B stores
    float invl = 1.0f / l_run;
    unsigned short* Wt = &Ks[0][0][0] + w * (16*72);   // 8 slabs x 2304B < 32KB
    #pragma unroll
    for (int c = 0; c < 4; ++c)
        #pragma unroll
        for (int r = 0; r < 4; ++r)
            Wt[(size_t)l16*72 + c*16 + quad*4 + r] = f2bf(oacc[c][r] * invl);
    __asm__ __volatile__("" ::: "memory");
    #pragma unroll
    for (int p = 0; p < 2; ++p) {
        int row = p*8 + (lane >> 3);
        int d0 = (lane & 7) * 8;
        int4 val = *(const int4*)&Wt[row*72 + d0];
        int tg = qt*64 + wq*16 + row;
        *(int4*)&yatt[((size_t)(b*TSEQ + tg))*CDIM + h*DHEAD + d0] = val;
    }
}

extern "C" void kernel_launch(void* const* d_in, const int* in_sizes, int n_in,
                              void* d_out, int out_size, void* d_ws, size_t ws_size,
                              hipStream_t stream) {
    const float* x   = (const float*)d_in[0];
    const float* Wq  = (const float*)d_in[1];
    const float* Wk  = (const float*)d_in[2];
    const float* Wv  = (const float*)d_in[3];
    const float* Wku = (const float*)d_in[4];
    const float* Wvu = (const float*)d_in[5];
    const float* Wc  = (const float*)d_in[6];

    float* out_y  = (float*)d_out;
    float* out_kl = out_y  + (size_t)MROWS * CDIM;
    float* out_vl = out_kl + (size_t)MROWS * NHEAD*DLAT;

    float* qproj = (float*)d_ws;                                           // 16 MB fp32
    unsigned short* xb   = (unsigned short*)(qproj + (size_t)MROWS*CDIM);  // 8 MB
    unsigned short* qb   = xb  + (size_t)MROWS*CDIM;                       // 8 MB
    unsigned short* kb   = qb  + (size_t)MROWS*CDIM;                       // 8 MB
    unsigned short* vt   = kb  + (size_t)MROWS*CDIM;                       // 8 MB
    unsigned short* wall = vt  + (size_t)MROWS*CDIM;                       // [Wq;Wk;Wv;Wc;Wku;Wvu]
    unsigned short* wcb  = wall + (size_t)2048*CDIM;
    unsigned short* wkub = wall + 3145728;
    unsigned short* wvub = wall + 3147776;
    unsigned short* yatt = (unsigned short*)qproj;   // alias: qproj dead after latup

    cvt_all<<<7172, 256, 0, stream>>>(x, Wq, Wk, Wv, Wc, Wku, Wvu, xb, wall);

    gemm_proj<<<dim3(2048/64, MROWS/128), 512, 0, stream>>>(
        xb, wall, qproj, out_kl, out_vl, CDIM);

    latup<<<dim3(TSEQ/64, NBATCH*NHEAD), 256, 0, stream>>>(
        qproj, out_kl, out_vl, wkub, wvub, qb, kb, vt);

    flash_attn<<<dim3(NBATCH*NHEAD, 16), 512, 0, stream>>>(qb, kb, vt, yatt);

    gemm_out<<<dim3(CDIM/64, MROWS/128), 512, 0, stream>>>(yatt, wcb, out_y, CDIM, CDIM);
}

// Round 11
// 185.415 us; speedup vs baseline: 1.0800x; 1.0336x over previous
//
#include <hip/hip_runtime.h>
#include <math.h>

#define NHEAD  16
#define DHEAD  64
#define DLAT   32
#define TSEQ   2048
#define NBATCH 2
#define CDIM   1024
#define MROWS  (NBATCH*TSEQ)   // 4096

typedef __attribute__((ext_vector_type(8))) short bf16x8;
typedef __attribute__((ext_vector_type(4))) short bf16x4;
typedef __attribute__((ext_vector_type(4))) float f32x4;

#define AS1 __attribute__((address_space(1)))
#define AS3 __attribute__((address_space(3)))

__device__ __forceinline__ unsigned short f2bf(float f) {
    union { float f; unsigned u; } v; v.f = f;
    unsigned r = v.u + 0x7fff + ((v.u >> 16) & 1);   // RNE
    return (unsigned short)(r >> 16);
}

// pack two floats -> bf16 pair (RNE), lo | hi<<16
__device__ __forceinline__ unsigned pk2(float lo, float hi) {
    return (unsigned)f2bf(lo) | ((unsigned)f2bf(hi) << 16);
}

// pack bf16(lo)|bf16(hi)<<16 by truncation — one v_perm_b32
__device__ __forceinline__ unsigned pack_trunc(float hi, float lo) {
    return __builtin_amdgcn_perm(__float_as_uint(hi), __float_as_uint(lo), 0x07060302u);
}

__device__ __forceinline__ void gld_lds16(const unsigned short* g, unsigned short* l) {
    __builtin_amdgcn_global_load_lds((const AS1 void*)g, (AS3 void*)l, 16, 0, 0);
}

// 16x16x16 bf16 MFMA: builtin if present, else raw instruction (gfx950 has it)
__device__ __forceinline__ f32x4 mfma_16x16x16_bf16(bf16x4 a, bf16x4 b, f32x4 c) {
#if __has_builtin(__builtin_amdgcn_mfma_f32_16x16x16bf16_1k)
    return __builtin_amdgcn_mfma_f32_16x16x16bf16_1k(a, b, c, 0, 0, 0);
#else
    asm volatile("v_mfma_f32_16x16x16_bf16 %0, %1, %2, %0\n\ts_nop 4"
                 : "+v"(c) : "v"(a), "v"(b));
    return c;
#endif
}

// ---------------- fp32 -> bf16: x and all six weights in ONE launch ----------------
__global__ __launch_bounds__(256) void cvt_all(
        const float* __restrict__ x,  const float* __restrict__ wq,
        const float* __restrict__ wk, const float* __restrict__ wv,
        const float* __restrict__ wc, const float* __restrict__ wku,
        const float* __restrict__ wvu,
        unsigned short* __restrict__ xb, unsigned short* __restrict__ wall) {
    int i = (blockIdx.x * 256 + threadIdx.x) * 4;
    const float* src; unsigned short* dst; int off;
    if      (i < 4194304) { src = x;   dst = xb;             off = 0;       }
    else if (i < 5242880) { src = wq;  dst = wall;           off = 4194304; }
    else if (i < 5767168) { src = wk;  dst = wall + 1048576; off = 5242880; }
    else if (i < 6291456) { src = wv;  dst = wall + 1572864; off = 5767168; }
    else if (i < 7340032) { src = wc;  dst = wall + 2097152; off = 6291456; }
    else if (i < 7342080) { src = wku; dst = wall + 3145728; off = 7340032; }
    else                  { src = wvu; dst = wall + 3147776; off = 7342080; }
    float4 v = *(const float4*)(src + (i - off));
    ushort4 o = { f2bf(v.x), f2bf(v.y), f2bf(v.z), f2bf(v.w) };
    *(ushort4*)(dst + (i - off)) = o;
}

// ---------------- MFMA GEMM core: 128x64 tile, BK=64, 8 waves, XOR-swizzled LDS ----------------
// R17: the old [.][32] tiles (64B rows) had ~8-way bank conflicts on every
// ds_read_b128 fragment read (lanes l16=0..15 at row-stride 64B -> bank start
// alternates {0,16}). Now [.][64] tiles (128B rows = full bank window) with
// flash's proven swizzle: phys colblk = logical ^ (row&7); DMA source is
// pre-swizzled, frag reads use fx0/fx1 (16 lanes -> 8 slots x 2 = 2-way = free
// per m136). BK 32->64 also halves the barrier count (16 K-iters, was 32).
__device__ __forceinline__ void gemm_core(
        const unsigned short* __restrict__ A, const unsigned short* __restrict__ W,
        int K, int bm, int bn, unsigned short* As, unsigned short* Bs,
        f32x4 (&acc)[2][2]) {
    const int tid = threadIdx.x;
    const int w = tid >> 6, lane = tid & 63;
    const int quad = lane >> 4, l16 = lane & 15;
    const int wm = (w >> 1) * 32, wn = (w & 1) * 32;

    // staging lane-mapping: lane covers 8 elems; row = +(lane>>3), colblk = lane&7
    // logical colblk = phys ^ (row&7)  (row&7 == lane>>3 since bases are x8)
    const int r8 = lane >> 3, c8 = lane & 7;
    const int scl = (c8 ^ r8) * 8;

    const unsigned short* Ag0 = A + (size_t)(bm +      w*8 + r8) * K + scl;
    const unsigned short* Ag1 = A + (size_t)(bm + 64 + w*8 + r8) * K + scl;
    const unsigned short* Wg0 = W + (size_t)(bn +      w*8 + r8) * K + scl;
    unsigned short* AsD0 = &As[(     w*8) * 64];
    unsigned short* AsD1 = &As[(64 + w*8) * 64];
    unsigned short* BsD  = &Bs[(     w*8) * 64];

    // swizzled fragment-read offsets (row&7 == l16&7: wm/t*16 are x16)
    const int fx0 = (quad ^ (l16 & 7)) * 8;
    const int fx1 = ((quad + 4) ^ (l16 & 7)) * 8;

    for (int k0 = 0; k0 < K; k0 += 64) {
        gld_lds16(Ag0 + k0, AsD0);
        gld_lds16(Ag1 + k0, AsD1);
        gld_lds16(Wg0 + k0, BsD);
        __syncthreads();
        bf16x8 af0[2], af1[2], bf0[2], bf1[2];
        #pragma unroll
        for (int t = 0; t < 2; ++t) {
            af0[t] = *(const bf16x8*)&As[(wm + t*16 + l16)*64 + fx0];
            af1[t] = *(const bf16x8*)&As[(wm + t*16 + l16)*64 + fx1];
        }
        #pragma unroll
        for (int c = 0; c < 2; ++c) {
            bf0[c] = *(const bf16x8*)&Bs[(wn + c*16 + l16)*64 + fx0];
            bf1[c] = *(const bf16x8*)&Bs[(wn + c*16 + l16)*64 + fx1];
        }
        #pragma unroll
        for (int t = 0; t < 2; ++t)
            #pragma unroll
            for (int c = 0; c < 2; ++c) {
                acc[t][c] = __builtin_amdgcn_mfma_f32_16x16x32_bf16(af0[t], bf0[c], acc[t][c], 0, 0, 0);
                acc[t][c] = __builtin_amdgcn_mfma_f32_16x16x32_bf16(af1[t], bf1[c], acc[t][c], 0, 0, 0);
            }
        __syncthreads();
    }
}

__global__ __launch_bounds__(512, 4) void gemm_proj(
        const unsigned short* __restrict__ A, const unsigned short* __restrict__ W,
        float* __restrict__ qproj, float* __restrict__ okl, float* __restrict__ ovl,
        int K) {
    __shared__ unsigned short As[128*64];   // 16 KB
    __shared__ unsigned short Bs[64*64];    // 8 KB
    const int bm = blockIdx.y * 128, bn = blockIdx.x * 64;
    f32x4 acc[2][2] = {};
    gemm_core(A, W, K, bm, bn, As, Bs, acc);

    const int tid = threadIdx.x;
    const int w = tid >> 6, lane = tid & 63;
    const int quad = lane >> 4, l16 = lane & 15;
    const int wm = (w >> 1) * 32, wn = (w & 1) * 32;

    float* base; int ldo;
    if (bn < 1024)      { base = qproj + bn;        ldo = 1024; }
    else if (bn < 1536) { base = okl + (bn - 1024); ldo = 512;  }
    else                { base = ovl + (bn - 1536); ldo = 512;  }

    #pragma unroll
    for (int t = 0; t < 2; ++t)
        #pragma unroll
        for (int c = 0; c < 2; ++c)
            #pragma unroll
            for (int r = 0; r < 4; ++r) {
                int row = bm + wm + t*16 + quad*4 + r;
                int col = wn + c*16 + l16;
                base[(size_t)row * ldo + col] = acc[t][c][r];
            }
}

__global__ __launch_bounds__(512, 4) void gemm_out(
        const unsigned short* __restrict__ A, const unsigned short* __restrict__ W,
        float* __restrict__ O, int N, int K) {
    __shared__ unsigned short As[128*64];   // 16 KB
    __shared__ unsigned short Bs[64*64];    // 8 KB
    const int bm = blockIdx.y * 128, bn = blockIdx.x * 64;
    f32x4 acc[2][2] = {};
    gemm_core(A, W, K, bm, bn, As, Bs, acc);

    const int tid = threadIdx.x;
    const int w = tid >> 6, lane = tid & 63;
    const int quad = lane >> 4, l16 = lane & 15;
    const int wm = (w >> 1) * 32, wn = (w & 1) * 32;
    #pragma unroll
    for (int t = 0; t < 2; ++t)
        #pragma unroll
        for (int c = 0; c < 2; ++c)
            #pragma unroll
            for (int r = 0; r < 4; ++r) {
                int row = bm + wm + t*16 + quad*4 + r;
                int col = bn + wn + c*16 + l16;
                O[(size_t)row * N + col] = acc[t][c][r];
            }
}

// ---------------- fused latent up-proj (k,v) via MFMA + q load + RoPE ----------------
// q carries 0.125*log2(e) so flash_attn's softmax runs in the exp2 domain.
#define QSCALE 0.18033688011112042f   // 0.125 * log2(e)
__global__ __launch_bounds__(256) void latup(
        const float* __restrict__ qproj, const float* __restrict__ klat,
        const float* __restrict__ vlat,
        const unsigned short* __restrict__ wkub, const unsigned short* __restrict__ wvub,
        unsigned short* __restrict__ qb, unsigned short* __restrict__ kb,
        unsigned short* __restrict__ vt) {
    __shared__ __attribute__((aligned(16))) unsigned short ksh[4][16][72];
    __shared__ __attribute__((aligned(16))) unsigned short qsh[4][16][72];
    __shared__ __attribute__((aligned(16))) unsigned short vsh[4][64][24];

    const int bh = blockIdx.y, b = bh >> 4, h = bh & 15;
    const int tid = threadIdx.x, w = tid >> 6, lane = tid & 63;
    const int quad = lane >> 4, l16 = lane & 15;
    const int tw = blockIdx.x * 64 + w * 16;   // wave's 16-token base
    const int t  = tw + l16;

    // B-frags (latents): row = token(l16), k = quad*8..+7 — 128 B/token across 4 lanes
    const float* klp = klat + ((size_t)(b*TSEQ + t))*(NHEAD*DLAT) + h*DLAT + quad*8;
    const float* vlp = vlat + ((size_t)(b*TSEQ + t))*(NHEAD*DLAT) + h*DLAT + quad*8;
    float4 kA = *(const float4*)klp, kB = *(const float4*)(klp + 4);
    float4 vA = *(const float4*)vlp, vB = *(const float4*)(vlp + 4);

    // A-frags (Wku/Wvu bf16): row = dim(c*16+l16), k = quad*8..+7
    bf16x8 xk[4], xv[4];
    #pragma unroll
    for (int c = 0; c < 4; ++c) {
        xk[c] = *(const bf16x8*)&wkub[(c*16 + l16)*DLAT + quad*8];
        xv[c] = *(const bf16x8*)&wvub[(c*16 + l16)*DLAT + quad*8];
    }

    union { bf16x8 v; unsigned u[4]; } yk, yv;
    yk.u[0] = pk2(kA.x, kA.y); yk.u[1] = pk2(kA.z, kA.w);
    yk.u[2] = pk2(kB.x, kB.y); yk.u[3] = pk2(kB.z, kB.w);
    yv.u[0] = pk2(vA.x, vA.y); yv.u[1] = pk2(vA.z, vA.w);
    yv.u[2] = pk2(vB.x, vB.y); yv.u[3] = pk2(vB.z, vB.w);

    f32x4 aK[4], aV[4];
    #pragma unroll
    for (int c = 0; c < 4; ++c) {
        f32x4 z = {0.f, 0.f, 0.f, 0.f};
        aK[c] = __builtin_amdgcn_mfma_f32_16x16x32_bf16(xk[c], yk.v, z, 0, 0, 0);
        aV[c] = __builtin_amdgcn_mfma_f32_16x16x32_bf16(xv[c], yv.v, z, 0, 0, 0);
    }

    // angles: dim d = (c&1)*16 + quad*4 + j, freq idx = d&31 — only 8 distinct/thread
    float C0[4], S0[4], C1[4], S1[4];
    const float tf = (float)t;
    #pragma unroll
    for (int j = 0; j < 4; ++j) {
        float f0 = (float)(quad*4 + j);
        __sincosf(tf * __expf(-f0 * 0.28782313662425572f),          &S0[j], &C0[j]);
        __sincosf(tf * __expf(-(f0 + 16.f) * 0.28782313662425572f), &S1[j], &C1[j]);
    }

    const float* qrow = qproj + ((size_t)(b*TSEQ + t))*CDIM + h*DHEAD;
    #pragma unroll
    for (int c = 0; c < 4; ++c) {
        const float* Cs = (c & 1) ? C1 : C0;
        const float* Ss = (c & 1) ? S1 : S0;
        float a0 = aK[c][0], a1 = aK[c][1], a2 = aK[c][2], a3 = aK[c][3];
        unsigned kw0 = pk2(a0*Cs[0] - a1*Ss[0], a1*Cs[1] + a0*Ss[1]);
        unsigned kw1 = pk2(a2*Cs[2] - a3*Ss[2], a3*Cs[3] + a2*Ss[3]);
        *(uint2*)&ksh[w][l16][c*16 + quad*4] = make_uint2(kw0, kw1);

        float4 qv = *(const float4*)(qrow + c*16 + quad*4);
        unsigned qw0 = pk2((qv.x*Cs[0] - qv.y*Ss[0])*QSCALE, (qv.y*Cs[1] + qv.x*Ss[1])*QSCALE);
        unsigned qw1 = pk2((qv.z*Cs[2] - qv.w*Ss[2])*QSCALE, (qv.w*Cs[3] + qv.z*Ss[3])*QSCALE);
        *(uint2*)&qsh[w][l16][c*16 + quad*4] = make_uint2(qw0, qw1);

        vsh[w][c*16 + quad*4 + 0][l16] = f2bf(aV[c][0]);
        vsh[w][c*16 + quad*4 + 1][l16] = f2bf(aV[c][1]);
        vsh[w][c*16 + quad*4 + 2][l16] = f2bf(aV[c][2]);
        vsh[w][c*16 + quad*4 + 3][l16] = f2bf(aV[c][3]);
    }

    // wave-local transpose: lockstep + drain LDS writes (no __syncthreads needed)
    __asm__ __volatile__("s_waitcnt lgkmcnt(0)" ::: "memory");

    const int ro = lane >> 2, co = (lane & 3) * 16;
    size_t go = ((size_t)bh*TSEQ + tw + ro)*DHEAD + co;
    int4 k0o = *(const int4*)&ksh[w][ro][co];
    int4 k1o = *(const int4*)&ksh[w][ro][co + 8];
    *(int4*)&kb[go]     = k0o;
    *(int4*)&kb[go + 8] = k1o;
    int4 q0o = *(const int4*)&qsh[w][ro][co];
    int4 q1o = *(const int4*)&qsh[w][ro][co + 8];
    *(int4*)&qb[go]     = q0o;
    *(int4*)&qb[go + 8] = q1o;

    size_t vo = ((size_t)bh*DHEAD + lane)*TSEQ + tw;
    int4 v0o = *(const int4*)&vsh[w][lane][0];
    int4 v1o = *(const int4*)&vsh[w][lane][8];
    *(int4*)&vt[vo]     = v0o;
    *(int4*)&vt[vo + 8] = v1o;
}

// ---------------- Flash attention: 8-wave blocks, wave-split qt pair (R10, 49.7us) ----------------
// R17: frozen — best-measured structure (Occ 35%, VALU 53% + MFMA 22% = 75%
// combined; approaching VALU-bound). Do not touch.
__device__ __forceinline__ void online_sm(f32x4 (&s)[8], float& m_run, float& l_run,
                                          f32x4 (&o)[4]) {
    float mx = -1e30f;
    #pragma unroll
    for (int c = 0; c < 8; ++c)
        #pragma unroll
        for (int r = 0; r < 4; ++r) mx = fmaxf(mx, s[c][r]);
    mx = fmaxf(mx, __shfl_xor(mx, 16, 64));
    mx = fmaxf(mx, __shfl_xor(mx, 32, 64));
    if (!__all(mx <= m_run + 8.f)) {   // defer-max: P bounded by 2^8
        float mn = fmaxf(m_run, mx);
        float alpha = __builtin_exp2f(m_run - mn);
        m_run = mn;
        l_run *= alpha;
        #pragma unroll
        for (int c = 0; c < 4; ++c)
            #pragma unroll
            for (int r = 0; r < 4; ++r) o[c][r] *= alpha;
    }
    float ls = 0.f;
    #pragma unroll
    for (int c = 0; c < 8; ++c)
        #pragma unroll
        for (int r = 0; r < 4; ++r) {
            float p = __builtin_exp2f(s[c][r] - m_run);
            s[c][r] = p;
            ls += p;
        }
    ls += __shfl_xor(ls, 16, 64);
    ls += __shfl_xor(ls, 32, 64);
    l_run += ls;
}

__global__ __launch_bounds__(512, 4) void flash_attn(
        const unsigned short* __restrict__ qb, const unsigned short* __restrict__ kb,
        const unsigned short* __restrict__ vtb, unsigned short* __restrict__ yatt) {
    const int bh = blockIdx.x;
    const int b = bh >> 4, h = bh & 15;

    __shared__ unsigned short Ks[2][128][64];    // 32 KB
    __shared__ unsigned short VTs[2][64][128];   // 32 KB

    const int tid  = threadIdx.x;
    const int w    = tid >> 6;          // 0..7
    const int lane = tid & 63;
    const int quad = lane >> 4;
    const int l16  = lane & 15;
    const bool heavy = (w >= 4);
    const int wq = w & 3;               // 16-row group within this wave's half

    const int qtA = blockIdx.y;          // 0..15 (light half)
    const int qtB = 31 - qtA;            // 16..31 (heavy half)
    const int qt  = heavy ? qtB : qtA;
    const int myN = (qt + 2) >> 1;       // KV 128-tiles this wave computes
    const int nB  = (qtB + 2) >> 1;      // loop bound (heavy side)

    const unsigned short* Kbase = kb  + (size_t)bh * TSEQ * DHEAD;
    const unsigned short* Vbase = vtb + (size_t)bh * DHEAD * TSEQ;

    // K DMA: wave w stages tile rows [w*16, w*16+16) — 2 issues x 8 rows
    const int kr8 = lane >> 3, kc8 = lane & 7;
    const int kcl = (kc8 ^ kr8) * 8;            // phys colblk = log ^ (row&7)
    // V DMA: wave w stages dim rows [w*8, w*8+8) — 2 issues x 4 rows
    const int vr4 = lane >> 4, vcp = lane & 15; // phys colblk = log ^ (row&15)

    // swizzled MFMA read offsets
    const int kx0 = (quad ^ (l16 & 7)) * 8;
    const int kx1 = ((quad + 4) ^ (l16 & 7)) * 8;
    const int vq = (quad >> 1), vodd = (quad & 1) * 4;

    const unsigned short* qbase =
        qb + ((size_t)bh*TSEQ + qt*64 + wq*16 + l16) * DHEAD + quad*8;
    bf16x8 q0 = *(const bf16x8*)qbase;
    bf16x8 q1 = *(const bf16x8*)(qbase + 32);

    f32x4 oacc[4] = {};
    float m_run = -1e30f, l_run = 0.f;

    #pragma unroll
    for (int i = 0; i < 2; ++i) {   // preload tile 0 into buf 0
        gld_lds16(Kbase + (size_t)(w*16 + i*8 + kr8)*DHEAD + kcl,
                  &Ks[0][w*16 + i*8][0]);
        int vrow = w*8 + i*4 + vr4;
        int vcl = (vcp ^ (vrow & 15)) * 8;
        gld_lds16(Vbase + (size_t)vrow*TSEQ + vcl, &VTs[0][w*8 + i*4][0]);
    }
    __syncthreads();

    for (int j = 0; j < nB; ++j) {
        const int buf = j & 1;
        if (j + 1 < nB) {   // async DMA prefetch of next tile into buf^1 (ALL waves)
            const int kc = (j + 1) * 128;
            #pragma unroll
            for (int i = 0; i < 2; ++i) {
                gld_lds16(Kbase + (size_t)(kc + w*16 + i*8 + kr8)*DHEAD + kcl,
                          &Ks[buf^1][w*16 + i*8][0]);
                int vrow = w*8 + i*4 + vr4;
                int vcl = (vcp ^ (vrow & 15)) * 8;
                gld_lds16(Vbase + (size_t)vrow*TSEQ + kc + vcl,
                          &VTs[buf^1][w*8 + i*4][0]);
            }
        }

        if (j < myN) {   // wave-uniform guard: light waves idle after their range
            // S^T = K Q^T (8 chunks of 16 K-rows), log2 units
            f32x4 s[8];
            __builtin_amdgcn_s_setprio(1);
            #pragma unroll
            for (int c = 0; c < 8; ++c) {
                bf16x8 ak0 = *(const bf16x8*)&Ks[buf][c*16 + l16][kx0];
                bf16x8 ak1 = *(const bf16x8*)&Ks[buf][c*16 + l16][kx1];
                f32x4 z = {0.f, 0.f, 0.f, 0.f};
                z = __builtin_amdgcn_mfma_f32_16x16x32_bf16(ak0, q0, z, 0, 0, 0);
                z = __builtin_amdgcn_mfma_f32_16x16x32_bf16(ak1, q1, z, 0, 0, 0);
                s[c] = z;
            }
            __builtin_amdgcn_s_setprio(0);

            if (j == myN - 1) {   // causal mask (covers the 128-overhang too)
                #pragma unroll
                for (int c = 0; c < 8; ++c)
                    #pragma unroll
                    for (int r = 0; r < 4; ++r)
                        if (j*128 + c*16 + quad*4 + r > qt*64 + wq*16 + l16)
                            s[c][r] = -1e30f;
            }

            online_sm(s, m_run, l_run, oacc);

            // PV: B-frag = packed P (k=quad*4+e matches 16x16x16), A = swizzled V^T
            __builtin_amdgcn_s_setprio(1);
            #pragma unroll
            for (int c = 0; c < 8; ++c) {
                union { bf16x4 v; unsigned u[2]; } bP;
                bP.u[0] = pack_trunc(s[c][1], s[c][0]);
                bP.u[1] = pack_trunc(s[c][3], s[c][2]);
                const int vcol = ((2*c + vq) ^ l16) * 8 + vodd;
                #pragma unroll
                for (int dc = 0; dc < 4; ++dc) {
                    bf16x4 av = *(const bf16x4*)&VTs[buf][dc*16 + l16][vcol];
                    oacc[dc] = mfma_16x16x16_bf16(av, bP.v, oacc[dc]);
                }
            }
            __builtin_amdgcn_s_setprio(0);
        }

        __syncthreads();   // drains prefetch DMA + protects buf reuse (all waves)
    }

    // epilogue: O^T -> O via per-wave LDS slab (stride 72), coalesced 16B stores
    float invl = 1.0f / l_run;
    unsigned short* Wt = &Ks[0][0][0] + w * (16*72);   // 8 slabs x 2304B < 32KB
    #pragma unroll
    for (int c = 0; c < 4; ++c)
        #pragma unroll
        for (int r = 0; r < 4; ++r)
            Wt[(size_t)l16*72 + c*16 + quad*4 + r] = f2bf(oacc[c][r] * invl);
    __asm__ __volatile__("" ::: "memory");
    #pragma unroll
    for (int p = 0; p < 2; ++p) {
        int row = p*8 + (lane >> 3);
        int d0 = (lane & 7) * 8;
        int4 val = *(const int4*)&Wt[row*72 + d0];
        int tg = qt*64 + wq*16 + row;
        *(int4*)&yatt[((size_t)(b*TSEQ + tg))*CDIM + h*DHEAD + d0] = val;
    }
}

extern "C" void kernel_launch(void* const* d_in, const int* in_sizes, int n_in,
                              void* d_out, int out_size, void* d_ws, size_t ws_size,
                              hipStream_t stream) {
    const float* x   = (const float*)d_in[0];
    const float* Wq  = (const float*)d_in[1];
    const float* Wk  = (const float*)d_in[2];
    const float* Wv  = (const float*)d_in[3];
    const float* Wku = (const float*)d_in[4];
    const float* Wvu = (const float*)d_in[5];
    const float* Wc  = (const float*)d_in[6];

    float* out_y  = (float*)d_out;
    float* out_kl = out_y  + (size_t)MROWS * CDIM;
    float* out_vl = out_kl + (size_t)MROWS * NHEAD*DLAT;

    float* qproj = (float*)d_ws;                                           // 16 MB fp32
    unsigned short* xb   = (unsigned short*)(qproj + (size_t)MROWS*CDIM);  // 8 MB
    unsigned short* qb   = xb  + (size_t)MROWS*CDIM;                       // 8 MB
    unsigned short* kb   = qb  + (size_t)MROWS*CDIM;                       // 8 MB
    unsigned short* vt   = kb  + (size_t)MROWS*CDIM;                       // 8 MB
    unsigned short* wall = vt  + (size_t)MROWS*CDIM;                       // [Wq;Wk;Wv;Wc;Wku;Wvu]
    unsigned short* wcb  = wall + (size_t)2048*CDIM;
    unsigned short* wkub = wall + 3145728;
    unsigned short* wvub = wall + 3147776;
    unsigned short* yatt = (unsigned short*)qproj;   // alias: qproj dead after latup

    cvt_all<<<7172, 256, 0, stream>>>(x, Wq, Wk, Wv, Wc, Wku, Wvu, xb, wall);

    gemm_proj<<<dim3(2048/64, MROWS/128), 512, 0, stream>>>(
        xb, wall, qproj, out_kl, out_vl, CDIM);

    latup<<<dim3(TSEQ/64, NBATCH*NHEAD), 256, 0, stream>>>(
        qproj, out_kl, out_vl, wkub, wvub, qb, kb, vt);

    flash_attn<<<dim3(NBATCH*NHEAD, 16), 512, 0, stream>>>(qb, kb, vt, yatt);

    gemm_out<<<dim3(CDIM/64, MROWS/128), 512, 0, stream>>>(yatt, wcb, out_y, CDIM, CDIM);
}